// Round 12
// baseline (629.901 us; speedup 1.0000x reference)
//
#include <hip/hip_runtime.h>
#include <cmath>

#define GN 2048
#define GB 16

typedef __attribute__((ext_vector_type(8))) short bf8_t;
typedef __attribute__((ext_vector_type(4))) float f4_t;

__device__ __forceinline__ short f2bf(float f) {
    union { float f; unsigned u; } v; v.f = f;
    unsigned r = v.u + 0x7FFFu + ((v.u >> 16) & 1u);
    return (short)(r >> 16);
}
__device__ __forceinline__ float bf2f(short s) {
    union { unsigned u; float f; } v; v.u = ((unsigned)(unsigned short)s) << 16;
    return v.f;
}

// async 16B/lane global->LDS (wave-uniform LDS base, lane i lands at base+i*16)
__device__ __forceinline__ void load16_lds(const short* g, short* l) {
    __builtin_amdgcn_global_load_lds(
        (const __attribute__((address_space(1))) unsigned int*)g,
        (__attribute__((address_space(3))) unsigned int*)l, 16, 0, 0);
}

// ---------------- reductions ----------------
__device__ __forceinline__ float wave_max(float v) {
#pragma unroll
    for (int o = 32; o > 0; o >>= 1) v = fmaxf(v, __shfl_xor(v, o, 64));
    return v;
}
__device__ __forceinline__ float block_max(float v) {
    __shared__ float sm[4];
    v = wave_max(v);
    if ((threadIdx.x & 63) == 0) sm[threadIdx.x >> 6] = v;
    __syncthreads();
    v = fmaxf(fmaxf(sm[0], sm[1]), fmaxf(sm[2], sm[3]));
    __syncthreads();
    return v;
}

// ---------------- fp32 -> bf16 convert ----------------
__global__ __launch_bounds__(256) void f2b_k(const float* __restrict__ s,
                                             short* __restrict__ d, int n) {
    int i = blockIdx.x * 256 + threadIdx.x;
    if (i < n) d[i] = f2bf(s[i]);
}

// ---------------- posenc + conv1 + relu -> h1T [32768, 128] bf16 ----------------
__global__ __launch_bounds__(256) void posenc_conv1_k(
    const float* __restrict__ x, const float* __restrict__ w1,
    const float* __restrict__ b1, short* __restrict__ h1) {
    __shared__ float w[128 * 21];
    __shared__ float bb[128];
    __shared__ float se[256][21];
    const int tid = threadIdx.x;
    for (int i = tid; i < 128 * 21; i += 256) w[i] = w1[i];
    if (tid < 128) bb[tid] = b1[tid];
    int p0 = blockIdx.x * 256;
    int p = p0 + tid, b = p >> 11, n = p & (GN - 1);
    const float* xb = x + (long)b * 3 * GN + n;
    float t0 = xb[0], t1 = xb[GN], t2 = xb[2 * GN];
    se[tid][0] = t0; se[tid][1] = t1; se[tid][2] = t2;
    se[tid][3] = sinf(t0); se[tid][4] = sinf(t1); se[tid][5] = sinf(t2);
    se[tid][6] = cosf(t0); se[tid][7] = cosf(t1); se[tid][8] = cosf(t2);
    se[tid][9] = sinf(2.f * t0); se[tid][10] = sinf(2.f * t1); se[tid][11] = sinf(2.f * t2);
    se[tid][12] = cosf(2.f * t0); se[tid][13] = cosf(2.f * t1); se[tid][14] = cosf(2.f * t2);
    se[tid][15] = sinf(4.f * t0); se[tid][16] = sinf(4.f * t1); se[tid][17] = sinf(4.f * t2);
    se[tid][18] = cosf(4.f * t0); se[tid][19] = cosf(4.f * t1); se[tid][20] = cosf(4.f * t2);
    __syncthreads();
    short* outb = h1 + (long)p0 * 128;
    for (int it = 0; it < 128; ++it) {
        int L = it * 256 + tid;
        int pl = L >> 7, o = L & 127;
        float s = bb[o];
        const float* er = se[pl];
        const float* wr = &w[o * 21];
#pragma unroll
        for (int c = 0; c < 21; ++c) s = fmaf(wr[c], er[c], s);
        outb[L] = f2bf(fmaxf(s, 0.f));
    }
}

// ---------------- MFMA GEMM: D[row,col] = sum_k A[row,k]*B[col,k] ----------------
// m97-class engine + double-buffered shared LDS: 256 threads, 128x128 block
// tile, BK=32, block-SHARED LDS staged cooperatively via global_load_lds (each
// tile DMA'd ONCE per block). 2 buffers (32 KB/block): DMAs for tile k+1 are
// issued BEFORE computing tile k, so DMA latency overlaps MFMA; one barrier
// per K-iter.
// CORRECTNESS (R10 post-mortem): __syncthreads() alone does NOT drain LDS-DMA
// vmcnt on this toolchain — each wave must explicitly s_waitcnt vmcnt(0)
// BEFORE signaling the barrier. Hazards: stage(t+1 -> buf^1) overwrites the
// buffer computed at t-1 (the barrier ending iter t-1 protects it); ds_reads
// of buf retire before the barrier via compiler lgkm dep-waits before MFMA.
// XOR-swizzled LDS: 16B-slot p of row holds k-block p ^ ((row>>1)&3)
// (conflict-free ds_read_b128, compatible with lane->base+lane*16 DMA placement).
// Grid: blockIdx.x = row tile (M/128), blockIdx.y = col tile (N/128), z = batch.
// MODE: 1=f32 out, 2=bf16 out, 4=Cb=bf16(aux - rs[row]*D), 5=col-max partials,
//       6=Cb=bf16(exp(D)) + per-tile row-sum partials into Pmax (rp).
// BIAS: 0 none, 1 per-col, 2 per-row, 3 per-col (cvec rows per batch).
template <int MODE, int BIAS, bool RELU>
__global__ __launch_bounds__(256) void mm_k(
    const short* __restrict__ A, int lda, long long aB,
    const short* __restrict__ B, int ldb, long long bB,
    const float* __restrict__ bias, int biasStride,
    const short* __restrict__ aux, long long auxB,
    const float* __restrict__ rsv,
    float* __restrict__ Cf, long long cfB,
    short* __restrict__ Cb, long long cbB,
    float* __restrict__ Pmax,
    int ldc, int K) {
    const int z = blockIdx.z;
    A += (long long)z * aB;
    B += (long long)z * bB;
    if (MODE == 4) { aux += (long long)z * auxB; rsv += (long long)z * GN; }
    if (MODE == 1) Cf += (long long)z * cfB;
    if (MODE == 2 || MODE == 4 || MODE == 6) Cb += (long long)z * cbB;
    if (MODE == 6) Pmax += (long long)z * GN * 32;
    const int row0 = blockIdx.x * 128, col0 = blockIdx.y * 128;
    const int tid = threadIdx.x;
    const int lane = tid & 63, w = tid >> 6;
    const int r = lane & 15, q = lane >> 4;
    const int wr = w >> 1, wc = w & 1;

    __shared__ short lA[8192];  // 2 bufs x [128 rows][32 k] swizzled, shared
    __shared__ short lB[8192];

    f4_t acc[4][4] = {};

    // cooperative staging: wave w covers rows w*32 .. w*32+31 (two 16-row DMAs)
    const int sRow = lane >> 2;                       // 0..15
    const int sKb = (lane & 3) ^ ((lane >> 3) & 3);   // swizzled source k-block
    const long aG = (long)(row0 + w * 32 + sRow) * lda + sKb * 8;
    const long bG = (long)(col0 + w * 32 + sRow) * ldb + sKb * 8;

    // swizzled k-invariant fragment read offsets (shorts)
    const int sw = (q ^ ((r >> 1) & 3)) * 8;
    int aoff[4], boff[4];
#pragma unroll
    for (int i = 0; i < 4; ++i) {
        aoff[i] = (wr * 64 + i * 16 + r) * 32 + sw;
        boff[i] = (wc * 64 + i * 16 + r) * 32 + sw;
    }

    auto stage = [&](int k0, int buf) {
        short* a = lA + buf * 4096 + (w * 32) * 32;
        short* b = lB + buf * 4096 + (w * 32) * 32;
        load16_lds(A + aG + k0, a);
        load16_lds(A + aG + (long)16 * lda + k0, a + 512);
        load16_lds(B + bG + k0, b);
        load16_lds(B + bG + (long)16 * ldb + k0, b + 512);
    };
    auto compute = [&](int buf) {
        const short* la = lA + buf * 4096;
        const short* lb = lB + buf * 4096;
        bf8_t av[4], bv[4];
#pragma unroll
        for (int i = 0; i < 4; ++i) av[i] = *(const bf8_t*)(la + aoff[i]);
#pragma unroll
        for (int j = 0; j < 4; ++j) bv[j] = *(const bf8_t*)(lb + boff[j]);
#pragma unroll
        for (int i = 0; i < 4; ++i)
#pragma unroll
            for (int j = 0; j < 4; ++j)
                acc[i][j] = __builtin_amdgcn_mfma_f32_16x16x32_bf16(av[i], bv[j], acc[i][j], 0, 0, 0);
    };

    stage(0, 0);
    asm volatile("s_waitcnt vmcnt(0)" ::: "memory");
    __syncthreads();
    int buf = 0;
    for (int k0 = 0; k0 < K; k0 += 32) {
        if (k0 + 32 < K) stage(k0 + 32, buf ^ 1);  // prefetch overlaps compute
        compute(buf);
        if (k0 + 32 < K) {
            asm volatile("s_waitcnt vmcnt(0)" ::: "memory");  // drain own DMAs
            __syncthreads();  // all waves drained + done reading buf
        }
        buf ^= 1;
    }

    if constexpr (MODE == 5) {
        // per-column max over this wave's 64 rows (pure shuffle)
        int b = row0 >> 11;
        int rw = (blockIdx.x * 2 + wr) & 31;  // row-wave index within batch
#pragma unroll
        for (int j = 0; j < 4; ++j) {
            float vm = -1e30f;
#pragma unroll
            for (int i = 0; i < 4; ++i)
#pragma unroll
                for (int e = 0; e < 4; ++e) vm = fmaxf(vm, acc[i][j][e]);
            vm = fmaxf(vm, __shfl_xor(vm, 16, 64));
            vm = fmaxf(vm, __shfl_xor(vm, 32, 64));
            if (q == 0) {
                int gcol = col0 + wc * 64 + j * 16 + r;
                Pmax[(((long)b * 1024 + gcol) << 5) + rw] = vm + bias[gcol];
            }
        }
    } else if constexpr (MODE == 6) {
        // P = exp(E) bf16 + per-tile row sums -> rp[row][blockIdx.y*2+wc]
        float rsum[4][4] = {};
#pragma unroll
        for (int j = 0; j < 4; ++j) {
            int gcol = col0 + wc * 64 + j * 16 + r;
#pragma unroll
            for (int i = 0; i < 4; ++i) {
#pragma unroll
                for (int e = 0; e < 4; ++e) {
                    int grow = row0 + wr * 64 + i * 16 + q * 4 + e;
                    float ex = __expf(acc[i][j][e]);
                    rsum[i][e] += ex;
                    Cb[(long)grow * ldc + gcol] = f2bf(ex);
                }
            }
        }
#pragma unroll
        for (int i = 0; i < 4; ++i)
#pragma unroll
            for (int e = 0; e < 4; ++e) {
                float v = rsum[i][e];
                v += __shfl_xor(v, 1, 64);
                v += __shfl_xor(v, 2, 64);
                v += __shfl_xor(v, 4, 64);
                v += __shfl_xor(v, 8, 64);
                if (r == 0) {
                    int grow = row0 + wr * 64 + i * 16 + q * 4 + e;
                    Pmax[((long)grow << 5) + blockIdx.y * 2 + wc] = v;
                }
            }
    } else if constexpr (MODE == 4) {
        // hs = bf16(aux - rs[row] * D)
#pragma unroll
        for (int i = 0; i < 4; ++i) {
#pragma unroll
            for (int e = 0; e < 4; ++e) {
                int grow = row0 + wr * 64 + i * 16 + q * 4 + e;
                float rsr = rsv[grow];
                long ob = (long)grow * ldc + col0 + wc * 64 + r;
#pragma unroll
                for (int j = 0; j < 4; ++j) {
                    long off = ob + j * 16;
                    Cb[off] = f2bf(bf2f(aux[off]) - acc[i][j][e] * rsr);
                }
            }
        }
    } else {
        const int b2d = (BIAS == 3) ? (row0 >> 11) : 0;
#pragma unroll
        for (int j = 0; j < 4; ++j) {
            int gcol = col0 + wc * 64 + j * 16 + r;
            float bvv = 0.f;
            if constexpr (BIAS == 1) bvv = bias[gcol];
            if constexpr (BIAS == 3) bvv = bias[b2d * biasStride + gcol];
#pragma unroll
            for (int i = 0; i < 4; ++i) {
#pragma unroll
                for (int e = 0; e < 4; ++e) {
                    int grow = row0 + wr * 64 + i * 16 + q * 4 + e;
                    float v = acc[i][j][e] + bvv;
                    if constexpr (BIAS == 2) v += bias[grow];
                    if constexpr (RELU) v = fmaxf(v, 0.f);
                    long off = (long)grow * ldc + gcol;
                    if constexpr (MODE == 1) Cf[off] = v;
                    if constexpr (MODE == 2) Cb[off] = f2bf(v);
                }
            }
        }
    }
}

// ---------------- rs[q] = 1 / sum of 32 row partials ----------------
__global__ __launch_bounds__(256) void rs_k(const float* __restrict__ rp,
                                            float* __restrict__ rs) {
    int i = blockIdx.x * 256 + threadIdx.x;  // 0..32767
    const float* p = rp + ((long)i << 5);
    float s = 0.f;
#pragma unroll
    for (int j = 0; j < 32; ++j) s += p[j];
    rs[i] = 1.f / s;
}

// ---------------- maxn over h2T bf16: two-stage ----------------
__global__ __launch_bounds__(256) void maxn1_k(const short* __restrict__ h2,
                                               float* __restrict__ gp) {
    int b = blockIdx.x, s = blockIdx.y, c = threadIdx.x;
    const short* p = h2 + ((long)b * GN + s * 128) * 256 + c;
    float m = -1e30f;
    for (int n = 0; n < 128; ++n) m = fmaxf(m, bf2f(p[(long)n * 256]));
    gp[((b * 16 + s) << 8) + c] = m;
}
__global__ __launch_bounds__(256) void maxn2_k(const float* __restrict__ gp,
                                               float* __restrict__ g) {
    int b = blockIdx.x, c = threadIdx.x;
    float m = -1e30f;
    for (int s = 0; s < 16; ++s) m = fmaxf(m, gp[((b * 16 + s) << 8) + c]);
    g[(b << 8) + c] = m;
}

// ---------------- cvec[b,o] = b3[o] + sum_c w3[o,256+c]*g[b,c] (fp32) ----------------
__global__ __launch_bounds__(256) void cvec_k(const float* __restrict__ w3,
                                              const float* __restrict__ b3,
                                              const float* __restrict__ g,
                                              float* __restrict__ cvec) {
    int idx = blockIdx.x * 256 + threadIdx.x;
    int b = idx >> 9, o = idx & 511;
    const float* gb = g + (b << 8);
    const float* wr = w3 + (long)o * 512 + 256;
    float s = b3[o];
    for (int c = 0; c < 256; ++c) s = fmaf(wr[c], gb[c], s);
    cvec[idx] = s;
}

// ---------------- column sums of attn = P * rs[q] over q (two-stage) ----------------
__global__ __launch_bounds__(256) void colsum1_k(const short* __restrict__ Ab,
                                                 const float* __restrict__ rs,
                                                 float* __restrict__ cp) {
    int kb = blockIdx.x, qs = blockIdx.y, z = blockIdx.z;
    int k = kb * 256 + threadIdx.x;
    const short* p = Ab + (long)z * GN * GN + (long)qs * 64 * GN + k;
    const float* rv = rs + z * GN + qs * 64;
    float s = 0.f;
    for (int qq = 0; qq < 64; ++qq) s += bf2f(p[(long)qq * GN]) * rv[qq];
    cp[((z * 32 + qs) * GN) + k] = s;
}
__global__ __launch_bounds__(256) void colsum2_k(const float* __restrict__ cp,
                                                 float* __restrict__ cs) {
    int k = blockIdx.x * 256 + threadIdx.x, z = blockIdx.y;
    float s = 1e-9f;
    for (int qs = 0; qs < 32; ++qs) s += cp[((z * 32 + qs) * GN) + k];
    cs[z * GN + k] = s;
}

// ---------------- xvc[c,p] /= cs[p]  (in place; folds L1 renorm into xv) ----------------
__global__ __launch_bounds__(256) void xvscale_k(short* __restrict__ xvc,
                                                 const float* __restrict__ cs) {
    long idx = ((long)blockIdx.x * 256 + threadIdx.x) * 4;  // over 512*32768
    int p = (int)(idx & 32767);
    short* ptr = xvc + idx;
    float4 cv = *(const float4*)(cs + p);
    uint2 u = *(const uint2*)ptr;
    short* sp = (short*)&u;
    sp[0] = f2bf(bf2f(sp[0]) / cv.x);
    sp[1] = f2bf(bf2f(sp[1]) / cv.y);
    sp[2] = f2bf(bf2f(sp[2]) / cv.z);
    sp[3] = f2bf(bf2f(sp[3]) / cv.w);
    *(uint2*)ptr = u;
}

// ---------------- BN stats two-stage on dTb bf16 [32768,512] ----------------
__global__ __launch_bounds__(256) void bn1_k(const short* __restrict__ d,
                                             float* __restrict__ bs1,
                                             float* __restrict__ bs2) {
    int s = blockIdx.x, t = threadIdx.x;
    const short* p = d + (long)s * 256 * 512 + t * 2;
    float s0 = 0.f, q0 = 0.f, s1 = 0.f, q1 = 0.f;
    for (int rr = 0; rr < 256; ++rr) {
        unsigned int u = *(const unsigned int*)(p + (long)rr * 512);
        float v0 = bf2f((short)(u & 0xffffu));
        float v1 = bf2f((short)(u >> 16));
        s0 += v0; q0 = fmaf(v0, v0, q0);
        s1 += v1; q1 = fmaf(v1, v1, q1);
    }
    bs1[s * 512 + t * 2] = s0; bs1[s * 512 + t * 2 + 1] = s1;
    bs2[s * 512 + t * 2] = q0; bs2[s * 512 + t * 2 + 1] = q1;
}
__global__ __launch_bounds__(256) void bn2_k(const float* __restrict__ bs1,
                                             const float* __restrict__ bs2,
                                             const float* __restrict__ gamma,
                                             const float* __restrict__ beta,
                                             float* __restrict__ sc,
                                             float* __restrict__ sh) {
    int c = blockIdx.x * 256 + threadIdx.x;
    float s = 0.f, s2 = 0.f;
    for (int i = 0; i < 128; ++i) {
        s += bs1[i * 512 + c];
        s2 += bs2[i * 512 + c];
    }
    const float cnt = (float)(GB * GN);
    float mu = s / cnt;
    float var = s2 / cnt - mu * mu;
    float r = rsqrtf(var + 1e-5f);
    float gm = gamma[c] * r;
    sc[c] = gm;
    sh[c] = beta[c] - gm * mu;
}

// ---------------- h4T = bf16(h3b + relu(d*sc+sh)) ----------------
__global__ __launch_bounds__(256) void bn_apply_k(const short* __restrict__ h3b,
                                                  const short* __restrict__ d,
                                                  const float* __restrict__ sc,
                                                  const float* __restrict__ sh,
                                                  short* __restrict__ h4) {
    long bidx = ((long)blockIdx.x * 256 + threadIdx.x) * 4;
    int c = (int)(bidx & 511);
    uint2 du = *(const uint2*)(d + bidx);
    short* ds = (short*)&du;
    uint2 hu = *(const uint2*)(h3b + bidx);
    short* hs = (short*)&hu;
    float4 a4 = *(const float4*)(sc + c);
    float4 b4 = *(const float4*)(sh + c);
    float r0 = bf2f(hs[0]) + fmaxf(fmaf(bf2f(ds[0]), a4.x, b4.x), 0.f);
    float r1 = bf2f(hs[1]) + fmaxf(fmaf(bf2f(ds[1]), a4.y, b4.y), 0.f);
    float r2 = bf2f(hs[2]) + fmaxf(fmaf(bf2f(ds[2]), a4.z, b4.z), 0.f);
    float r3 = bf2f(hs[3]) + fmaxf(fmaf(bf2f(ds[3]), a4.w, b4.w), 0.f);
    uint2 o;
    o.x = (unsigned short)f2bf(r0) | ((unsigned)(unsigned short)f2bf(r1) << 16);
    o.y = (unsigned short)f2bf(r2) | ((unsigned)(unsigned short)f2bf(r3) << 16);
    *(uint2*)(h4 + bidx) = o;
}

// ---------------- out[i] = max over 32 partials ----------------
__global__ __launch_bounds__(256) void max_final_k(const float* __restrict__ P,
                                                   float* __restrict__ out) {
    int i = blockIdx.x * 256 + threadIdx.x;
    const float* p = P + ((long)i << 5);
    float m = p[0];
#pragma unroll
    for (int j = 1; j < 32; ++j) m = fmaxf(m, p[j]);
    out[i] = m;
}

extern "C" void kernel_launch(void* const* d_in, const int* in_sizes, int n_in,
                              void* d_out, int out_size, void* d_ws, size_t ws_size,
                              hipStream_t stream) {
    const float* x = (const float*)d_in[0];
    const float* w1 = (const float*)d_in[1];
    const float* b1 = (const float*)d_in[2];
    const float* w2 = (const float*)d_in[3];
    const float* b2 = (const float*)d_in[4];
    const float* w3 = (const float*)d_in[5];
    const float* b3 = (const float*)d_in[6];
    const float* w4 = (const float*)d_in[7];
    const float* b4 = (const float*)d_in[8];
    const float* wqk = (const float*)d_in[9];
    const float* wv = (const float*)d_in[10];
    const float* bv = (const float*)d_in[11];
    const float* wt = (const float*)d_in[12];
    const float* bt = (const float*)d_in[13];
    const float* gamma = (const float*)d_in[14];
    const float* beta = (const float*)d_in[15];
    float* out = (float*)d_out;

    // ---- workspace carve (bytes), peak ~253.5 MB (unchanged from R8) ----
    char* base = (char*)d_ws;
    short* h3b = (short*)base;                    // [32768,512] bf16 32 MB
    short* hsT = (short*)(base + 33554432);       // [32768,512] bf16 32 MB
    short* kT  = (short*)(base + 67108864);       // [32768,128] bf16  8 MB
    short* xvc = (short*)(base + 75497472);       // [512,32768] bf16 32 MB (channel-major)
    short* EA  = (short*)(base + 109051904);      // [16,2048,2048] bf16 128 MB (P = exp(E))
    short* h1T = (short*)(base + 109051904);      //   alias (early, dead before EA)
    short* h2T = (short*)(base + 117440512);      //   alias (early)
    short* dTb = (short*)(base + 109051904);      //   alias [32768,512] bf16 (late, EA dead)
    short* h4T = (short*)(base + 67108864);       //   alias 32 MB over kT+xvc (late)
    char* S = base + 243269632;
    float* gp   = (float*)(S);                    // 262144
    float* g    = (float*)(S + 262144);           // 16384
    float* cvec = (float*)(S + 278528);           // 32768
    float* cp   = (float*)(S + 311296);           // 4 MB [16,32,2048]; rp aliases (earlier)
    float* rp   = cp;                             //   [32768,32] row-sum partials (dead before cp)
    float* cs   = (float*)(S + 4505600);          // 128 KB [16,2048]
    float* bs1  = (float*)(S + 4636672);          // 262144
    float* bs2  = (float*)(S + 4898816);          // 262144
    float* bnsc = (float*)(S + 5160960);          // 2048
    float* bnsh = (float*)(S + 5163008);          // 2048
    float* Pmax = (float*)(S + 5165056);          // [16,1024,32] f32 = 2 MB
    short* w2b  = (short*)(S + 7262208);
    short* w3b  = (short*)(S + 7327744);
    short* wqkb = (short*)(S + 7852032);
    short* wvb  = (short*)(S + 7983104);
    short* wtb  = (short*)(S + 8507392);
    short* w4b  = (short*)(S + 9031680);
    float* rs   = (float*)(S + 10080256);         // 128 KB [16,2048] 1/rowsum

    // 0. weight converts to bf16
    f2b_k<<<128, 256, 0, stream>>>(w2, w2b, 256 * 128);
    f2b_k<<<1024, 256, 0, stream>>>(w3, w3b, 512 * 512);
    f2b_k<<<256, 256, 0, stream>>>(wqk, wqkb, 128 * 512);
    f2b_k<<<1024, 256, 0, stream>>>(wv, wvb, 512 * 512);
    f2b_k<<<1024, 256, 0, stream>>>(wt, wtb, 512 * 512);
    f2b_k<<<2048, 256, 0, stream>>>(w4, w4b, 1024 * 512);

    // 1. posenc + conv1 + relu -> h1T
    posenc_conv1_k<<<128, 256, 0, stream>>>(x, w1, b1, h1T);

    // 2. h2T = h1T @ w2^T + b2  (no relu)
    mm_k<2, 1, false><<<dim3(256, 2, 1), 256, 0, stream>>>(
        h1T, 128, 0, w2b, 128, 0, b2, 0, nullptr, 0, nullptr,
        nullptr, 0, h2T, 0, nullptr, 256, 128);

    // 3. g[b,c] = max_n h2T
    maxn1_k<<<dim3(GB, 16), 256, 0, stream>>>(h2T, gp);
    maxn2_k<<<GB, 256, 0, stream>>>(gp, g);

    // 4. cvec = w3[:,256:] @ g + b3 (fp32)
    cvec_k<<<32, 256, 0, stream>>>(w3, b3, g, cvec);

    // 5. h3b = bf16(relu(h2T @ w3[:,:256]^T + cvec))
    mm_k<2, 3, true><<<dim3(256, 4, 1), 256, 0, stream>>>(
        h2T, 256, 0, w3b, 512, 0, cvec, 512, nullptr, 0, nullptr,
        nullptr, 0, h3b, 0, nullptr, 512, 256);

    // 6. kT = h3b @ wqk^T
    mm_k<2, 0, false><<<dim3(256, 1, 1), 256, 0, stream>>>(
        h3b, 512, 0, wqkb, 512, 0, nullptr, 0, nullptr, 0, nullptr,
        nullptr, 0, kT, 0, nullptr, 128, 512);

    // 7. xv channel-major: D[c, point] = wv @ h3 + bv(row)
    mm_k<2, 2, false><<<dim3(4, 256, 1), 256, 0, stream>>>(
        wvb, 512, 0, h3b, 512, 0, bv, 0, nullptr, 0, nullptr,
        nullptr, 0, xvc, 0, nullptr, 32768, 512);

    // 8. attention, all 16 batches, softmax fused into energy epilogue
    // 8a. P = exp(kT kT^T) bf16 + row-sum partials rp
    mm_k<6, 0, false><<<dim3(16, 16, 16), 256, 0, stream>>>(
        kT, 128, (long long)GN * 128, kT, 128, (long long)GN * 128,
        nullptr, 0, nullptr, 0, nullptr, nullptr, 0,
        EA, (long long)GN * GN, rp, GN, 128);
    // 8b. rs = 1/rowsum
    rs_k<<<128, 256, 0, stream>>>(rp, rs);
    // 8c. column sums of attn = P*rs
    colsum1_k<<<dim3(8, 32, GB), 256, 0, stream>>>(EA, rs, cp);
    colsum2_k<<<dim3(8, GB), 256, 0, stream>>>(cp, cs);
    // 8d. fold L1 renorm into xv (in place)
    xvscale_k<<<16384, 256, 0, stream>>>(xvc, cs);
    // 8e. hsT = bf16(h3b - rs[q] * (P @ xv'^T))
    mm_k<4, 0, false><<<dim3(16, 4, 16), 256, 0, stream>>>(
        EA, GN, (long long)GN * GN,
        xvc, 32768, (long long)GN,
        nullptr, 0,
        h3b, (long long)GN * 512, rs,
        nullptr, 0,
        hsT, (long long)GN * 512,
        nullptr, 512, GN);

    // 9. dTb = bf16(hsT @ wt^T + bt)
    mm_k<2, 1, false><<<dim3(256, 4, 1), 256, 0, stream>>>(
        hsT, 512, 0, wtb, 512, 0, bt, 0, nullptr, 0, nullptr,
        nullptr, 0, dTb, 0, nullptr, 512, 512);

    // 10. BN stats
    bn1_k<<<128, 256, 0, stream>>>(dTb, bs1, bs2);
    bn2_k<<<2, 256, 0, stream>>>(bs1, bs2, gamma, beta, bnsc, bnsh);

    // 11. h4T = bf16(h3b + relu(bn(dTb)))
    bn_apply_k<<<16384, 256, 0, stream>>>(h3b, dTb, bnsc, bnsh, h4T);

    // 12. fused final conv + per-wave-tile col max -> Pmax [16,1024,32]
    mm_k<5, 1, false><<<dim3(256, 8, 1), 256, 0, stream>>>(
        h4T, 512, 0, w4b, 512, 0, b4, 0, nullptr, 0, nullptr,
        nullptr, 0, nullptr, 0, Pmax, 1024, 512);

    // 13. out = max over tiles
    max_final_k<<<64, 256, 0, stream>>>(Pmax, out);
}

// Round 13
// 573.695 us; speedup vs baseline: 1.0980x; 1.0980x over previous
//
#include <hip/hip_runtime.h>
#include <cmath>

#define GN 2048
#define GB 16

typedef __attribute__((ext_vector_type(8))) short bf8_t;
typedef __attribute__((ext_vector_type(4))) float f4_t;

__device__ __forceinline__ short f2bf(float f) {
    union { float f; unsigned u; } v; v.f = f;
    unsigned r = v.u + 0x7FFFu + ((v.u >> 16) & 1u);
    return (short)(r >> 16);
}
__device__ __forceinline__ float bf2f(short s) {
    union { unsigned u; float f; } v; v.u = ((unsigned)(unsigned short)s) << 16;
    return v.f;
}

// async 16B/lane global->LDS (wave-uniform LDS base, lane i lands at base+i*16)
__device__ __forceinline__ void load16_lds(const short* g, short* l) {
    __builtin_amdgcn_global_load_lds(
        (const __attribute__((address_space(1))) unsigned int*)g,
        (__attribute__((address_space(3))) unsigned int*)l, 16, 0, 0);
}

// ---------------- reductions ----------------
__device__ __forceinline__ float wave_max(float v) {
#pragma unroll
    for (int o = 32; o > 0; o >>= 1) v = fmaxf(v, __shfl_xor(v, o, 64));
    return v;
}
__device__ __forceinline__ float block_max(float v) {
    __shared__ float sm[4];
    v = wave_max(v);
    if ((threadIdx.x & 63) == 0) sm[threadIdx.x >> 6] = v;
    __syncthreads();
    v = fmaxf(fmaxf(sm[0], sm[1]), fmaxf(sm[2], sm[3]));
    __syncthreads();
    return v;
}

// ---------------- fused fp32 -> bf16 weight convert (dst region contiguous) ----------------
__global__ __launch_bounds__(256) void f2ball_k(
    const float* __restrict__ w2, const float* __restrict__ w3,
    const float* __restrict__ wqk, const float* __restrict__ wv,
    const float* __restrict__ wt, const float* __restrict__ w4,
    short* __restrict__ dst) {
    int i = blockIdx.x * 256 + threadIdx.x;
    if (i >= 1409024) return;
    float v;
    if (i < 32768) v = w2[i];
    else if (i < 294912) v = w3[i - 32768];
    else if (i < 360448) v = wqk[i - 294912];
    else if (i < 622592) v = wv[i - 360448];
    else if (i < 884736) v = wt[i - 622592];
    else v = w4[i - 884736];
    dst[i] = f2bf(v);
}

// ---------------- posenc + conv1 + relu -> h1T [32768, 128] bf16 ----------------
__global__ __launch_bounds__(256) void posenc_conv1_k(
    const float* __restrict__ x, const float* __restrict__ w1,
    const float* __restrict__ b1, short* __restrict__ h1) {
    __shared__ float w[128 * 21];
    __shared__ float bb[128];
    __shared__ float se[256][21];
    const int tid = threadIdx.x;
    for (int i = tid; i < 128 * 21; i += 256) w[i] = w1[i];
    if (tid < 128) bb[tid] = b1[tid];
    int p0 = blockIdx.x * 256;
    int p = p0 + tid, b = p >> 11, n = p & (GN - 1);
    const float* xb = x + (long)b * 3 * GN + n;
    float t0 = xb[0], t1 = xb[GN], t2 = xb[2 * GN];
    se[tid][0] = t0; se[tid][1] = t1; se[tid][2] = t2;
    se[tid][3] = sinf(t0); se[tid][4] = sinf(t1); se[tid][5] = sinf(t2);
    se[tid][6] = cosf(t0); se[tid][7] = cosf(t1); se[tid][8] = cosf(t2);
    se[tid][9] = sinf(2.f * t0); se[tid][10] = sinf(2.f * t1); se[tid][11] = sinf(2.f * t2);
    se[tid][12] = cosf(2.f * t0); se[tid][13] = cosf(2.f * t1); se[tid][14] = cosf(2.f * t2);
    se[tid][15] = sinf(4.f * t0); se[tid][16] = sinf(4.f * t1); se[tid][17] = sinf(4.f * t2);
    se[tid][18] = cosf(4.f * t0); se[tid][19] = cosf(4.f * t1); se[tid][20] = cosf(4.f * t2);
    __syncthreads();
    short* outb = h1 + (long)p0 * 128;
    for (int it = 0; it < 128; ++it) {
        int L = it * 256 + tid;
        int pl = L >> 7, o = L & 127;
        float s = bb[o];
        const float* er = se[pl];
        const float* wr = &w[o * 21];
#pragma unroll
        for (int c = 0; c < 21; ++c) s = fmaf(wr[c], er[c], s);
        outb[L] = f2bf(fmaxf(s, 0.f));
    }
}

// ---------------- MFMA GEMM: D[row,col] = sum_k A[row,k]*B[col,k] ----------------
// R11 engine (measured best): 256 threads, 128x128 block tile, BK=32,
// block-SHARED single-buffered LDS (A 8 KB + B 8 KB) staged cooperatively via
// global_load_lds (each tile DMA'd ONCE per block), 2-barrier K-loop.
// CORRECTNESS: each wave must explicitly s_waitcnt vmcnt(0) BEFORE signaling
// the barrier (LDS-DMA is not drained by __syncthreads on this toolchain).
// 16 KB LDS/block -> high residency; barrier drain of one block overlaps MFMA
// of co-resident blocks.
// XOR-swizzled LDS: 16B-slot p of row holds k-block p ^ ((row>>1)&3).
// Grid: blockIdx.x = row tile (M/128), blockIdx.y = col tile (N/128), z = batch.
// MODE: 1=f32 out, 2=bf16 out, 4=Cb=bf16(aux - rs[row]*D), 5=col-max partials,
//       6=Cb=bf16(exp(D)) + per-tile row-sum partials into Pmax (rp).
// BIAS: 0 none, 1 per-col, 2 per-row, 3 per-col (cvec rows per batch).
// STATS (MODE 2 only): also emit per-column (sum, sum^2) over this wave's 64
// rows into Ps1/Ps2[rw2*512 + gcol], rw2 = blockIdx.x*2+wr — fuses BN stats.
template <int MODE, int BIAS, bool RELU, bool STATS = false>
__global__ __launch_bounds__(256) void mm_k(
    const short* __restrict__ A, int lda, long long aB,
    const short* __restrict__ B, int ldb, long long bB,
    const float* __restrict__ bias, int biasStride,
    const short* __restrict__ aux, long long auxB,
    const float* __restrict__ rsv,
    float* __restrict__ Cf, long long cfB,
    short* __restrict__ Cb, long long cbB,
    float* __restrict__ Pmax, float* __restrict__ Ps2,
    int ldc, int K) {
    const int z = blockIdx.z;
    A += (long long)z * aB;
    B += (long long)z * bB;
    if (MODE == 4) { aux += (long long)z * auxB; rsv += (long long)z * GN; }
    if (MODE == 1) Cf += (long long)z * cfB;
    if (MODE == 2 || MODE == 4 || MODE == 6) Cb += (long long)z * cbB;
    if (MODE == 6) Pmax += (long long)z * GN * 32;
    const int row0 = blockIdx.x * 128, col0 = blockIdx.y * 128;
    const int tid = threadIdx.x;
    const int lane = tid & 63, w = tid >> 6;
    const int r = lane & 15, q = lane >> 4;
    const int wr = w >> 1, wc = w & 1;

    __shared__ short lA[4096];  // [128 rows][32 k] swizzled, shared by block
    __shared__ short lB[4096];

    f4_t acc[4][4] = {};

    // cooperative staging: wave w covers rows w*32 .. w*32+31 (two 16-row DMAs)
    const int sRow = lane >> 2;                       // 0..15
    const int sKb = (lane & 3) ^ ((lane >> 3) & 3);   // swizzled source k-block
    const long aG = (long)(row0 + w * 32 + sRow) * lda + sKb * 8;
    const long bG = (long)(col0 + w * 32 + sRow) * ldb + sKb * 8;
    short* ldsA0 = lA + (w * 32) * 32;
    short* ldsA1 = lA + (w * 32 + 16) * 32;
    short* ldsB0 = lB + (w * 32) * 32;
    short* ldsB1 = lB + (w * 32 + 16) * 32;

    // swizzled k-invariant fragment read offsets (shorts)
    const int sw = (q ^ ((r >> 1) & 3)) * 8;
    int aoff[4], boff[4];
#pragma unroll
    for (int i = 0; i < 4; ++i) {
        aoff[i] = (wr * 64 + i * 16 + r) * 32 + sw;
        boff[i] = (wc * 64 + i * 16 + r) * 32 + sw;
    }

    for (int k0 = 0; k0 < K; k0 += 32) {
        __syncthreads();  // previous tile fully consumed (lgkm dep-waits before MFMA use)
        load16_lds(A + aG + k0, ldsA0);
        load16_lds(A + aG + (long)16 * lda + k0, ldsA1);
        load16_lds(B + bG + k0, ldsB0);
        load16_lds(B + bG + (long)16 * ldb + k0, ldsB1);
        asm volatile("s_waitcnt vmcnt(0)" ::: "memory");  // DRAIN own LDS-DMA before barrier
        __syncthreads();  // all waves drained -> full tile visible
        bf8_t av[4], bv[4];
#pragma unroll
        for (int i = 0; i < 4; ++i) av[i] = *(const bf8_t*)(lA + aoff[i]);
#pragma unroll
        for (int j = 0; j < 4; ++j) bv[j] = *(const bf8_t*)(lB + boff[j]);
#pragma unroll
        for (int i = 0; i < 4; ++i)
#pragma unroll
            for (int j = 0; j < 4; ++j)
                acc[i][j] = __builtin_amdgcn_mfma_f32_16x16x32_bf16(av[i], bv[j], acc[i][j], 0, 0, 0);
    }

    if constexpr (MODE == 5) {
        // per-column max over this wave's 64 rows (pure shuffle)
        int b = row0 >> 11;
        int rw = (blockIdx.x * 2 + wr) & 31;  // row-wave index within batch
#pragma unroll
        for (int j = 0; j < 4; ++j) {
            float vm = -1e30f;
#pragma unroll
            for (int i = 0; i < 4; ++i)
#pragma unroll
                for (int e = 0; e < 4; ++e) vm = fmaxf(vm, acc[i][j][e]);
            vm = fmaxf(vm, __shfl_xor(vm, 16, 64));
            vm = fmaxf(vm, __shfl_xor(vm, 32, 64));
            if (q == 0) {
                int gcol = col0 + wc * 64 + j * 16 + r;
                Pmax[(((long)b * 1024 + gcol) << 5) + rw] = vm + bias[gcol];
            }
        }
    } else if constexpr (MODE == 6) {
        // P = exp(E) bf16 + per-tile row sums -> rp[row][blockIdx.y*2+wc]
        float rsum[4][4] = {};
#pragma unroll
        for (int j = 0; j < 4; ++j) {
            int gcol = col0 + wc * 64 + j * 16 + r;
#pragma unroll
            for (int i = 0; i < 4; ++i) {
#pragma unroll
                for (int e = 0; e < 4; ++e) {
                    int grow = row0 + wr * 64 + i * 16 + q * 4 + e;
                    float ex = __expf(acc[i][j][e]);
                    rsum[i][e] += ex;
                    Cb[(long)grow * ldc + gcol] = f2bf(ex);
                }
            }
        }
#pragma unroll
        for (int i = 0; i < 4; ++i)
#pragma unroll
            for (int e = 0; e < 4; ++e) {
                float v = rsum[i][e];
                v += __shfl_xor(v, 1, 64);
                v += __shfl_xor(v, 2, 64);
                v += __shfl_xor(v, 4, 64);
                v += __shfl_xor(v, 8, 64);
                if (r == 0) {
                    int grow = row0 + wr * 64 + i * 16 + q * 4 + e;
                    Pmax[((long)grow << 5) + blockIdx.y * 2 + wc] = v;
                }
            }
    } else if constexpr (MODE == 4) {
        // hs = bf16(aux - rs[row] * D)
#pragma unroll
        for (int i = 0; i < 4; ++i) {
#pragma unroll
            for (int e = 0; e < 4; ++e) {
                int grow = row0 + wr * 64 + i * 16 + q * 4 + e;
                float rsr = rsv[grow];
                long ob = (long)grow * ldc + col0 + wc * 64 + r;
#pragma unroll
                for (int j = 0; j < 4; ++j) {
                    long off = ob + j * 16;
                    Cb[off] = f2bf(bf2f(aux[off]) - acc[i][j][e] * rsr);
                }
            }
        }
    } else {
        const int b2d = (BIAS == 3) ? (row0 >> 11) : 0;
#pragma unroll
        for (int j = 0; j < 4; ++j) {
            int gcol = col0 + wc * 64 + j * 16 + r;
            float bvv = 0.f;
            if constexpr (BIAS == 1) bvv = bias[gcol];
            if constexpr (BIAS == 3) bvv = bias[b2d * biasStride + gcol];
            float s1 = 0.f, s2 = 0.f;
#pragma unroll
            for (int i = 0; i < 4; ++i) {
#pragma unroll
                for (int e = 0; e < 4; ++e) {
                    int grow = row0 + wr * 64 + i * 16 + q * 4 + e;
                    float v = acc[i][j][e] + bvv;
                    if constexpr (BIAS == 2) v += bias[grow];
                    if constexpr (RELU) v = fmaxf(v, 0.f);
                    if constexpr (STATS) { s1 += v; s2 = fmaf(v, v, s2); }
                    long off = (long)grow * ldc + gcol;
                    if constexpr (MODE == 1) Cf[off] = v;
                    if constexpr (MODE == 2) Cb[off] = f2bf(v);
                }
            }
            if constexpr (STATS) {
                s1 += __shfl_xor(s1, 16, 64); s1 += __shfl_xor(s1, 32, 64);
                s2 += __shfl_xor(s2, 16, 64); s2 += __shfl_xor(s2, 32, 64);
                if (q == 0) {
                    int rw2 = blockIdx.x * 2 + wr;  // 0..511 row-wave index
                    Pmax[rw2 * 512 + gcol] = s1;
                    Ps2[rw2 * 512 + gcol] = s2;
                }
            }
        }
    }
}

// ---------------- rs[q] = 1 / sum of 32 row partials ----------------
__global__ __launch_bounds__(256) void rs_k(const float* __restrict__ rp,
                                            float* __restrict__ rs) {
    int i = blockIdx.x * 256 + threadIdx.x;  // 0..32767
    const float* p = rp + ((long)i << 5);
    float s = 0.f;
#pragma unroll
    for (int j = 0; j < 32; ++j) s += p[j];
    rs[i] = 1.f / s;
}

// ---------------- maxn over h2T bf16: two-stage ----------------
__global__ __launch_bounds__(256) void maxn1_k(const short* __restrict__ h2,
                                               float* __restrict__ gp) {
    int b = blockIdx.x, s = blockIdx.y, c = threadIdx.x;
    const short* p = h2 + ((long)b * GN + s * 128) * 256 + c;
    float m = -1e30f;
    for (int n = 0; n < 128; ++n) m = fmaxf(m, bf2f(p[(long)n * 256]));
    gp[((b * 16 + s) << 8) + c] = m;
}
__global__ __launch_bounds__(256) void maxn2_k(const float* __restrict__ gp,
                                               float* __restrict__ g) {
    int b = blockIdx.x, c = threadIdx.x;
    float m = -1e30f;
    for (int s = 0; s < 16; ++s) m = fmaxf(m, gp[((b * 16 + s) << 8) + c]);
    g[(b << 8) + c] = m;
}

// ---------------- cvec[b,o] = b3[o] + sum_c w3[o,256+c]*g[b,c] (fp32) ----------------
__global__ __launch_bounds__(256) void cvec_k(const float* __restrict__ w3,
                                              const float* __restrict__ b3,
                                              const float* __restrict__ g,
                                              float* __restrict__ cvec) {
    int idx = blockIdx.x * 256 + threadIdx.x;
    int b = idx >> 9, o = idx & 511;
    const float* gb = g + (b << 8);
    const float* wr = w3 + (long)o * 512 + 256;
    float s = b3[o];
    for (int c = 0; c < 256; ++c) s = fmaf(wr[c], gb[c], s);
    cvec[idx] = s;
}

// ---------------- column sums of attn = P * rs[q] over q (two-stage) ----------------
__global__ __launch_bounds__(256) void colsum1_k(const short* __restrict__ Ab,
                                                 const float* __restrict__ rs,
                                                 float* __restrict__ cp) {
    int kb = blockIdx.x, qs = blockIdx.y, z = blockIdx.z;
    int k = kb * 256 + threadIdx.x;
    const short* p = Ab + (long)z * GN * GN + (long)qs * 64 * GN + k;
    const float* rv = rs + z * GN + qs * 64;
    float s = 0.f;
    for (int qq = 0; qq < 64; ++qq) s += bf2f(p[(long)qq * GN]) * rv[qq];
    cp[((z * 32 + qs) * GN) + k] = s;
}
__global__ __launch_bounds__(256) void colsum2_k(const float* __restrict__ cp,
                                                 float* __restrict__ cs) {
    int k = blockIdx.x * 256 + threadIdx.x, z = blockIdx.y;
    float s = 1e-9f;
    for (int qs = 0; qs < 32; ++qs) s += cp[((z * 32 + qs) * GN) + k];
    cs[z * GN + k] = s;
}

// ---------------- xvc[c,p] /= cs[p]  (in place; folds L1 renorm into xv) ----------------
__global__ __launch_bounds__(256) void xvscale_k(short* __restrict__ xvc,
                                                 const float* __restrict__ cs) {
    long idx = ((long)blockIdx.x * 256 + threadIdx.x) * 4;  // over 512*32768
    int p = (int)(idx & 32767);
    short* ptr = xvc + idx;
    float4 cv = *(const float4*)(cs + p);
    uint2 u = *(const uint2*)ptr;
    short* sp = (short*)&u;
    sp[0] = f2bf(bf2f(sp[0]) / cv.x);
    sp[1] = f2bf(bf2f(sp[1]) / cv.y);
    sp[2] = f2bf(bf2f(sp[2]) / cv.z);
    sp[3] = f2bf(bf2f(sp[3]) / cv.w);
    *(uint2*)ptr = u;
}

// ---------------- BN scale/shift from fused GEMM stats [512][512] ----------------
__global__ __launch_bounds__(256) void bn2_k(const float* __restrict__ bs1,
                                             const float* __restrict__ bs2,
                                             const float* __restrict__ gamma,
                                             const float* __restrict__ beta,
                                             float* __restrict__ sc,
                                             float* __restrict__ sh) {
    int c = blockIdx.x * 256 + threadIdx.x;
    float s = 0.f, s2 = 0.f;
    for (int i = 0; i < 512; ++i) {
        s += bs1[i * 512 + c];
        s2 += bs2[i * 512 + c];
    }
    const float cnt = (float)(GB * GN);
    float mu = s / cnt;
    float var = s2 / cnt - mu * mu;
    float r = rsqrtf(var + 1e-5f);
    float gm = gamma[c] * r;
    sc[c] = gm;
    sh[c] = beta[c] - gm * mu;
}

// ---------------- h4T = bf16(h3b + relu(d*sc+sh)) ----------------
__global__ __launch_bounds__(256) void bn_apply_k(const short* __restrict__ h3b,
                                                  const short* __restrict__ d,
                                                  const float* __restrict__ sc,
                                                  const float* __restrict__ sh,
                                                  short* __restrict__ h4) {
    long bidx = ((long)blockIdx.x * 256 + threadIdx.x) * 4;
    int c = (int)(bidx & 511);
    uint2 du = *(const uint2*)(d + bidx);
    short* ds = (short*)&du;
    uint2 hu = *(const uint2*)(h3b + bidx);
    short* hs = (short*)&hu;
    float4 a4 = *(const float4*)(sc + c);
    float4 b4 = *(const float4*)(sh + c);
    float r0 = bf2f(hs[0]) + fmaxf(fmaf(bf2f(ds[0]), a4.x, b4.x), 0.f);
    float r1 = bf2f(hs[1]) + fmaxf(fmaf(bf2f(ds[1]), a4.y, b4.y), 0.f);
    float r2 = bf2f(hs[2]) + fmaxf(fmaf(bf2f(ds[2]), a4.z, b4.z), 0.f);
    float r3 = bf2f(hs[3]) + fmaxf(fmaf(bf2f(ds[3]), a4.w, b4.w), 0.f);
    uint2 o;
    o.x = (unsigned short)f2bf(r0) | ((unsigned)(unsigned short)f2bf(r1) << 16);
    o.y = (unsigned short)f2bf(r2) | ((unsigned)(unsigned short)f2bf(r3) << 16);
    *(uint2*)(h4 + bidx) = o;
}

// ---------------- out[i] = max over 32 partials ----------------
__global__ __launch_bounds__(256) void max_final_k(const float* __restrict__ P,
                                                   float* __restrict__ out) {
    int i = blockIdx.x * 256 + threadIdx.x;
    const float* p = P + ((long)i << 5);
    float m = p[0];
#pragma unroll
    for (int j = 1; j < 32; ++j) m = fmaxf(m, p[j]);
    out[i] = m;
}

extern "C" void kernel_launch(void* const* d_in, const int* in_sizes, int n_in,
                              void* d_out, int out_size, void* d_ws, size_t ws_size,
                              hipStream_t stream) {
    const float* x = (const float*)d_in[0];
    const float* w1 = (const float*)d_in[1];
    const float* b1 = (const float*)d_in[2];
    const float* w2 = (const float*)d_in[3];
    const float* b2 = (const float*)d_in[4];
    const float* w3 = (const float*)d_in[5];
    const float* b3 = (const float*)d_in[6];
    const float* w4 = (const float*)d_in[7];
    const float* b4 = (const float*)d_in[8];
    const float* wqk = (const float*)d_in[9];
    const float* wv = (const float*)d_in[10];
    const float* bv = (const float*)d_in[11];
    const float* wt = (const float*)d_in[12];
    const float* bt = (const float*)d_in[13];
    const float* gamma = (const float*)d_in[14];
    const float* beta = (const float*)d_in[15];
    float* out = (float*)d_out;

    // ---- workspace carve (bytes), peak ~255.05 MB ----
    char* base = (char*)d_ws;
    short* h3b = (short*)base;                    // [32768,512] bf16 32 MB
    short* hsT = (short*)(base + 33554432);       // [32768,512] bf16 32 MB
    short* kT  = (short*)(base + 67108864);       // [32768,128] bf16  8 MB
    short* xvc = (short*)(base + 75497472);       // [512,32768] bf16 32 MB (channel-major)
    short* EA  = (short*)(base + 109051904);      // [16,2048,2048] bf16 128 MB (P = exp(E))
    short* h1T = (short*)(base + 109051904);      //   alias (early, dead before EA)
    short* h2T = (short*)(base + 117440512);      //   alias (early)
    short* dTb = (short*)(base + 109051904);      //   alias [32768,512] bf16 (late, EA dead)
    short* h4T = (short*)(base + 67108864);       //   alias 32 MB over kT+xvc (late)
    char* S = base + 243269632;
    float* gp   = (float*)(S);                    // 262144
    float* g    = (float*)(S + 262144);           // 16384
    float* cvec = (float*)(S + 278528);           // 32768
    float* cp   = (float*)(S + 311296);           // 4 MB [16,32,2048]; rp aliases (earlier)
    float* rp   = cp;                             //   [32768,32] row-sum partials (dead before cp)
    float* cs   = (float*)(S + 4505600);          // 128 KB [16,2048]
    float* bs1  = (float*)(S + 4636672);          // 1 MB [512,512] fused BN sum partials
    float* bs2  = (float*)(S + 5685248);          // 1 MB [512,512] fused BN sumsq partials
    float* bnsc = (float*)(S + 6733824);          // 2048
    float* bnsh = (float*)(S + 6735872);          // 2048
    float* Pmax = (float*)(S + 6737920);          // [16,1024,32] f32 = 2 MB
    short* w2b  = (short*)(S + 8835072);          // bf16 weights, CONTIGUOUS region:
    short* w3b  = (short*)(S + 8900608);          //   w2 32768 | w3 262144 | wqk 65536
    short* wqkb = (short*)(S + 9424896);          //   wv 262144 | wt 262144 | w4 524288
    short* wvb  = (short*)(S + 9555968);
    short* wtb  = (short*)(S + 10080256);
    short* w4b  = (short*)(S + 10604544);
    float* rs   = (float*)(S + 11653120);         // 128 KB [16,2048] 1/rowsum

    // 0. all weight converts in one kernel (dst region contiguous from w2b)
    f2ball_k<<<5505, 256, 0, stream>>>(w2, w3, wqk, wv, wt, w4, w2b);

    // 1. posenc + conv1 + relu -> h1T
    posenc_conv1_k<<<128, 256, 0, stream>>>(x, w1, b1, h1T);

    // 2. h2T = h1T @ w2^T + b2  (no relu)
    mm_k<2, 1, false><<<dim3(256, 2, 1), 256, 0, stream>>>(
        h1T, 128, 0, w2b, 128, 0, b2, 0, nullptr, 0, nullptr,
        nullptr, 0, h2T, 0, nullptr, nullptr, 256, 128);

    // 3. g[b,c] = max_n h2T
    maxn1_k<<<dim3(GB, 16), 256, 0, stream>>>(h2T, gp);
    maxn2_k<<<GB, 256, 0, stream>>>(gp, g);

    // 4. cvec = w3[:,256:] @ g + b3 (fp32)
    cvec_k<<<32, 256, 0, stream>>>(w3, b3, g, cvec);

    // 5. h3b = bf16(relu(h2T @ w3[:,:256]^T + cvec))
    mm_k<2, 3, true><<<dim3(256, 4, 1), 256, 0, stream>>>(
        h2T, 256, 0, w3b, 512, 0, cvec, 512, nullptr, 0, nullptr,
        nullptr, 0, h3b, 0, nullptr, nullptr, 512, 256);

    // 6. kT = h3b @ wqk^T
    mm_k<2, 0, false><<<dim3(256, 1, 1), 256, 0, stream>>>(
        h3b, 512, 0, wqkb, 512, 0, nullptr, 0, nullptr, 0, nullptr,
        nullptr, 0, kT, 0, nullptr, nullptr, 128, 512);

    // 7. xv channel-major: D[c, point] = wv @ h3 + bv(row)
    mm_k<2, 2, false><<<dim3(4, 256, 1), 256, 0, stream>>>(
        wvb, 512, 0, h3b, 512, 0, bv, 0, nullptr, 0, nullptr,
        nullptr, 0, xvc, 0, nullptr, nullptr, 32768, 512);

    // 8. attention, all 16 batches, softmax fused into energy epilogue
    // 8a. P = exp(kT kT^T) bf16 + row-sum partials rp
    mm_k<6, 0, false><<<dim3(16, 16, 16), 256, 0, stream>>>(
        kT, 128, (long long)GN * 128, kT, 128, (long long)GN * 128,
        nullptr, 0, nullptr, 0, nullptr, nullptr, 0,
        EA, (long long)GN * GN, rp, nullptr, GN, 128);
    // 8b. rs = 1/rowsum
    rs_k<<<128, 256, 0, stream>>>(rp, rs);
    // 8c. column sums of attn = P*rs
    colsum1_k<<<dim3(8, 32, GB), 256, 0, stream>>>(EA, rs, cp);
    colsum2_k<<<dim3(8, GB), 256, 0, stream>>>(cp, cs);
    // 8d. fold L1 renorm into xv (in place)
    xvscale_k<<<16384, 256, 0, stream>>>(xvc, cs);
    // 8e. hsT = bf16(h3b - rs[q] * (P @ xv'^T))
    mm_k<4, 0, false><<<dim3(16, 4, 16), 256, 0, stream>>>(
        EA, GN, (long long)GN * GN,
        xvc, 32768, (long long)GN,
        nullptr, 0,
        h3b, (long long)GN * 512, rs,
        nullptr, 0,
        hsT, (long long)GN * 512,
        nullptr, nullptr, 512, GN);

    // 9. dTb = bf16(hsT @ wt^T + bt) + fused BN stat partials (bs1/bs2)
    mm_k<2, 1, false, true><<<dim3(256, 4, 1), 256, 0, stream>>>(
        hsT, 512, 0, wtb, 512, 0, bt, 0, nullptr, 0, nullptr,
        nullptr, 0, dTb, 0, bs1, bs2, 512, 512);

    // 10. BN scale/shift from fused stats
    bn2_k<<<2, 256, 0, stream>>>(bs1, bs2, gamma, beta, bnsc, bnsh);

    // 11. h4T = bf16(h3b + relu(bn(dTb)))
    bn_apply_k<<<16384, 256, 0, stream>>>(h3b, dTb, bnsc, bnsh, h4T);

    // 12. fused final conv + per-wave-tile col max -> Pmax [16,1024,32]
    mm_k<5, 1, false><<<dim3(256, 8, 1), 256, 0, stream>>>(
        h4T, 512, 0, w4b, 512, 0, b4, 0, nullptr, 0, nullptr,
        nullptr, 0, nullptr, 0, Pmax, nullptr, 1024, 512);

    // 13. out = max over tiles
    max_final_k<<<64, 256, 0, stream>>>(Pmax, out);
}

// Round 14
// 510.841 us; speedup vs baseline: 1.2331x; 1.1230x over previous
//
#include <hip/hip_runtime.h>
#include <cmath>

#define GN 2048
#define GB 16

typedef __attribute__((ext_vector_type(8))) short bf8_t;
typedef __attribute__((ext_vector_type(4))) float f4_t;

__device__ __forceinline__ short f2bf(float f) {
    union { float f; unsigned u; } v; v.f = f;
    unsigned r = v.u + 0x7FFFu + ((v.u >> 16) & 1u);
    return (short)(r >> 16);
}
__device__ __forceinline__ float bf2f(short s) {
    union { unsigned u; float f; } v; v.u = ((unsigned)(unsigned short)s) << 16;
    return v.f;
}

// async 16B/lane global->LDS (wave-uniform LDS base, lane i lands at base+i*16)
__device__ __forceinline__ void load16_lds(const short* g, short* l) {
    __builtin_amdgcn_global_load_lds(
        (const __attribute__((address_space(1))) unsigned int*)g,
        (__attribute__((address_space(3))) unsigned int*)l, 16, 0, 0);
}

// ---------------- reductions ----------------
__device__ __forceinline__ float wave_max(float v) {
#pragma unroll
    for (int o = 32; o > 0; o >>= 1) v = fmaxf(v, __shfl_xor(v, o, 64));
    return v;
}
__device__ __forceinline__ float wave_sum(float v) {
#pragma unroll
    for (int o = 32; o > 0; o >>= 1) v += __shfl_xor(v, o, 64);
    return v;
}
__device__ __forceinline__ float block_max(float v) {
    __shared__ float sm[4];
    v = wave_max(v);
    if ((threadIdx.x & 63) == 0) sm[threadIdx.x >> 6] = v;
    __syncthreads();
    v = fmaxf(fmaxf(sm[0], sm[1]), fmaxf(sm[2], sm[3]));
    __syncthreads();
    return v;
}
__device__ __forceinline__ float block_sum(float v) {
    __shared__ float sm[4];
    v = wave_sum(v);
    if ((threadIdx.x & 63) == 0) sm[threadIdx.x >> 6] = v;
    __syncthreads();
    v = sm[0] + sm[1] + sm[2] + sm[3];
    __syncthreads();
    return v;
}

// ---------------- fused fp32 -> bf16 weight convert (dst region contiguous) ----------------
__global__ __launch_bounds__(256) void f2ball_k(
    const float* __restrict__ w2, const float* __restrict__ w3,
    const float* __restrict__ wqk, const float* __restrict__ wv,
    const float* __restrict__ wt, const float* __restrict__ w4,
    short* __restrict__ dst) {
    int i = blockIdx.x * 256 + threadIdx.x;
    if (i >= 1409024) return;
    float v;
    if (i < 32768) v = w2[i];
    else if (i < 294912) v = w3[i - 32768];
    else if (i < 360448) v = wqk[i - 294912];
    else if (i < 622592) v = wv[i - 360448];
    else if (i < 884736) v = wt[i - 622592];
    else v = w4[i - 884736];
    dst[i] = f2bf(v);
}

// ---------------- posenc + conv1 + relu -> h1T [32768, 128] bf16 ----------------
__global__ __launch_bounds__(256) void posenc_conv1_k(
    const float* __restrict__ x, const float* __restrict__ w1,
    const float* __restrict__ b1, short* __restrict__ h1) {
    __shared__ float w[128 * 21];
    __shared__ float bb[128];
    __shared__ float se[256][21];
    const int tid = threadIdx.x;
    for (int i = tid; i < 128 * 21; i += 256) w[i] = w1[i];
    if (tid < 128) bb[tid] = b1[tid];
    int p0 = blockIdx.x * 256;
    int p = p0 + tid, b = p >> 11, n = p & (GN - 1);
    const float* xb = x + (long)b * 3 * GN + n;
    float t0 = xb[0], t1 = xb[GN], t2 = xb[2 * GN];
    se[tid][0] = t0; se[tid][1] = t1; se[tid][2] = t2;
    se[tid][3] = sinf(t0); se[tid][4] = sinf(t1); se[tid][5] = sinf(t2);
    se[tid][6] = cosf(t0); se[tid][7] = cosf(t1); se[tid][8] = cosf(t2);
    se[tid][9] = sinf(2.f * t0); se[tid][10] = sinf(2.f * t1); se[tid][11] = sinf(2.f * t2);
    se[tid][12] = cosf(2.f * t0); se[tid][13] = cosf(2.f * t1); se[tid][14] = cosf(2.f * t2);
    se[tid][15] = sinf(4.f * t0); se[tid][16] = sinf(4.f * t1); se[tid][17] = sinf(4.f * t2);
    se[tid][18] = cosf(4.f * t0); se[tid][19] = cosf(4.f * t1); se[tid][20] = cosf(4.f * t2);
    __syncthreads();
    short* outb = h1 + (long)p0 * 128;
    for (int it = 0; it < 128; ++it) {
        int L = it * 256 + tid;
        int pl = L >> 7, o = L & 127;
        float s = bb[o];
        const float* er = se[pl];
        const float* wr = &w[o * 21];
#pragma unroll
        for (int c = 0; c < 21; ++c) s = fmaf(wr[c], er[c], s);
        outb[L] = f2bf(fmaxf(s, 0.f));
    }
}

// ---------------- MFMA GEMM: D[row,col] = sum_k A[row,k]*B[col,k] ----------------
// R11 engine, BK=64: 256 threads, 128x128 block tile, block-SHARED
// single-buffered LDS staged cooperatively via global_load_lds, 2-barrier
// K-loop. Each iteration stages TWO back-to-back BK=32 sub-tiles (identical
// R11 lane mapping + XOR swizzle, second sub-tile at +4096 shorts) and runs
// 32 MFMAs per barrier pair — halves barrier/drain events vs BK=32.
// CORRECTNESS: each wave must explicitly s_waitcnt vmcnt(0) BEFORE signaling
// the barrier (LDS-DMA is not drained by __syncthreads on this toolchain).
// 32 KB LDS/block. XOR-swizzled: 16B-slot p of row holds k-block p^((row>>1)&3).
// Grid: blockIdx.x = row tile (M/128), blockIdx.y = col tile (N/128), z = batch.
// MODE: 1=f32 out, 2=bf16 out, 4=Cb=bf16(aux - rs[row]*D), 5=col-max partials,
//       6=Cb=bf16(exp(D)) + per-tile row-sum partials into Pmax (rp).
// BIAS: 0 none, 1 per-col, 2 per-row, 3 per-col (cvec rows per batch).
// STATS (MODE 2 only): emit per-column (sum,sum^2) over this wave's 64 rows
// into Pmax/Ps2[rw2*512+gcol], rw2 = blockIdx.x*2+wr — fuses BN stats.
template <int MODE, int BIAS, bool RELU, bool STATS = false>
__global__ __launch_bounds__(256) void mm_k(
    const short* __restrict__ A, int lda, long long aB,
    const short* __restrict__ B, int ldb, long long bB,
    const float* __restrict__ bias, int biasStride,
    const short* __restrict__ aux, long long auxB,
    const float* __restrict__ rsv,
    float* __restrict__ Cf, long long cfB,
    short* __restrict__ Cb, long long cbB,
    float* __restrict__ Pmax, float* __restrict__ Ps2,
    int ldc, int K) {
    const int z = blockIdx.z;
    A += (long long)z * aB;
    B += (long long)z * bB;
    if (MODE == 4) { aux += (long long)z * auxB; rsv += (long long)z * GN; }
    if (MODE == 1) Cf += (long long)z * cfB;
    if (MODE == 2 || MODE == 4 || MODE == 6) Cb += (long long)z * cbB;
    if (MODE == 6) Pmax += (long long)z * GN * 32;
    const int row0 = blockIdx.x * 128, col0 = blockIdx.y * 128;
    const int tid = threadIdx.x;
    const int lane = tid & 63, w = tid >> 6;
    const int r = lane & 15, q = lane >> 4;
    const int wr = w >> 1, wc = w & 1;

    __shared__ short lA[8192];  // 2 sub-tiles x [128 rows][32 k] swizzled
    __shared__ short lB[8192];

    f4_t acc[4][4] = {};

    // cooperative staging: wave w covers rows w*32 .. w*32+31 (two 16-row DMAs
    // per operand per sub-tile)
    const int sRow = lane >> 2;                       // 0..15
    const int sKb = (lane & 3) ^ ((lane >> 3) & 3);   // swizzled source k-block
    const long aG = (long)(row0 + w * 32 + sRow) * lda + sKb * 8;
    const long bG = (long)(col0 + w * 32 + sRow) * ldb + sKb * 8;
    short* ldsA0 = lA + (w * 32) * 32;
    short* ldsA1 = lA + (w * 32 + 16) * 32;
    short* ldsB0 = lB + (w * 32) * 32;
    short* ldsB1 = lB + (w * 32 + 16) * 32;

    // swizzled k-invariant fragment read offsets (shorts, within one sub-tile)
    const int sw = (q ^ ((r >> 1) & 3)) * 8;
    int aoff[4], boff[4];
#pragma unroll
    for (int i = 0; i < 4; ++i) {
        aoff[i] = (wr * 64 + i * 16 + r) * 32 + sw;
        boff[i] = (wc * 64 + i * 16 + r) * 32 + sw;
    }

    for (int k0 = 0; k0 < K; k0 += 64) {
        __syncthreads();  // previous tile fully consumed (lgkm dep-waits before MFMA use)
        load16_lds(A + aG + k0, ldsA0);
        load16_lds(A + aG + (long)16 * lda + k0, ldsA1);
        load16_lds(B + bG + k0, ldsB0);
        load16_lds(B + bG + (long)16 * ldb + k0, ldsB1);
        load16_lds(A + aG + k0 + 32, ldsA0 + 4096);
        load16_lds(A + aG + (long)16 * lda + k0 + 32, ldsA1 + 4096);
        load16_lds(B + bG + k0 + 32, ldsB0 + 4096);
        load16_lds(B + bG + (long)16 * ldb + k0 + 32, ldsB1 + 4096);
        asm volatile("s_waitcnt vmcnt(0)" ::: "memory");  // DRAIN own LDS-DMA before barrier
        __syncthreads();  // all waves drained -> full tile visible
#pragma unroll
        for (int h = 0; h < 2; ++h) {
            const short* la = lA + h * 4096;
            const short* lb = lB + h * 4096;
            bf8_t av[4], bv[4];
#pragma unroll
            for (int i = 0; i < 4; ++i) av[i] = *(const bf8_t*)(la + aoff[i]);
#pragma unroll
            for (int j = 0; j < 4; ++j) bv[j] = *(const bf8_t*)(lb + boff[j]);
#pragma unroll
            for (int i = 0; i < 4; ++i)
#pragma unroll
                for (int j = 0; j < 4; ++j)
                    acc[i][j] = __builtin_amdgcn_mfma_f32_16x16x32_bf16(av[i], bv[j], acc[i][j], 0, 0, 0);
        }
    }

    if constexpr (MODE == 5) {
        // per-column max over this wave's 64 rows (pure shuffle)
        int b = row0 >> 11;
        int rw = (blockIdx.x * 2 + wr) & 31;  // row-wave index within batch
#pragma unroll
        for (int j = 0; j < 4; ++j) {
            float vm = -1e30f;
#pragma unroll
            for (int i = 0; i < 4; ++i)
#pragma unroll
                for (int e = 0; e < 4; ++e) vm = fmaxf(vm, acc[i][j][e]);
            vm = fmaxf(vm, __shfl_xor(vm, 16, 64));
            vm = fmaxf(vm, __shfl_xor(vm, 32, 64));
            if (q == 0) {
                int gcol = col0 + wc * 64 + j * 16 + r;
                Pmax[(((long)b * 1024 + gcol) << 5) + rw] = vm + bias[gcol];
            }
        }
    } else if constexpr (MODE == 6) {
        // P = exp(E) bf16 + per-tile row sums -> rp[row][blockIdx.y*2+wc]
        float rsum[4][4] = {};
#pragma unroll
        for (int j = 0; j < 4; ++j) {
            int gcol = col0 + wc * 64 + j * 16 + r;
#pragma unroll
            for (int i = 0; i < 4; ++i) {
#pragma unroll
                for (int e = 0; e < 4; ++e) {
                    int grow = row0 + wr * 64 + i * 16 + q * 4 + e;
                    float ex = __expf(acc[i][j][e]);
                    rsum[i][e] += ex;
                    Cb[(long)grow * ldc + gcol] = f2bf(ex);
                }
            }
        }
#pragma unroll
        for (int i = 0; i < 4; ++i)
#pragma unroll
            for (int e = 0; e < 4; ++e) {
                float v = rsum[i][e];
                v += __shfl_xor(v, 1, 64);
                v += __shfl_xor(v, 2, 64);
                v += __shfl_xor(v, 4, 64);
                v += __shfl_xor(v, 8, 64);
                if (r == 0) {
                    int grow = row0 + wr * 64 + i * 16 + q * 4 + e;
                    Pmax[((long)grow << 5) + blockIdx.y * 2 + wc] = v;
                }
            }
    } else if constexpr (MODE == 4) {
        // hs = bf16(aux - rs[row] * D)
#pragma unroll
        for (int i = 0; i < 4; ++i) {
#pragma unroll
            for (int e = 0; e < 4; ++e) {
                int grow = row0 + wr * 64 + i * 16 + q * 4 + e;
                float rsr = rsv[grow];
                long ob = (long)grow * ldc + col0 + wc * 64 + r;
#pragma unroll
                for (int j = 0; j < 4; ++j) {
                    long off = ob + j * 16;
                    Cb[off] = f2bf(bf2f(aux[off]) - acc[i][j][e] * rsr);
                }
            }
        }
    } else {
        const int b2d = (BIAS == 3) ? (row0 >> 11) : 0;
#pragma unroll
        for (int j = 0; j < 4; ++j) {
            int gcol = col0 + wc * 64 + j * 16 + r;
            float bvv = 0.f;
            if constexpr (BIAS == 1) bvv = bias[gcol];
            if constexpr (BIAS == 3) bvv = bias[b2d * biasStride + gcol];
            float s1 = 0.f, s2 = 0.f;
#pragma unroll
            for (int i = 0; i < 4; ++i) {
#pragma unroll
                for (int e = 0; e < 4; ++e) {
                    int grow = row0 + wr * 64 + i * 16 + q * 4 + e;
                    float v = acc[i][j][e] + bvv;
                    if constexpr (BIAS == 2) v += bias[grow];
                    if constexpr (RELU) v = fmaxf(v, 0.f);
                    if constexpr (STATS) { s1 += v; s2 = fmaf(v, v, s2); }
                    long off = (long)grow * ldc + gcol;
                    if constexpr (MODE == 1) Cf[off] = v;
                    if constexpr (MODE == 2) Cb[off] = f2bf(v);
                }
            }
            if constexpr (STATS) {
                s1 += __shfl_xor(s1, 16, 64); s1 += __shfl_xor(s1, 32, 64);
                s2 += __shfl_xor(s2, 16, 64); s2 += __shfl_xor(s2, 32, 64);
                if (q == 0) {
                    int rw2 = blockIdx.x * 2 + wr;  // 0..511 row-wave index
                    Pmax[rw2 * 512 + gcol] = s1;
                    Ps2[rw2 * 512 + gcol] = s2;
                }
            }
        }
    }
}

// ---------------- rs[q] = 1 / sum of 32 row partials ----------------
__global__ __launch_bounds__(256) void rs_k(const float* __restrict__ rp,
                                            float* __restrict__ rs) {
    int i = blockIdx.x * 256 + threadIdx.x;  // 0..32767
    const float* p = rp + ((long)i << 5);
    float s = 0.f;
#pragma unroll
    for (int j = 0; j < 32; ++j) s += p[j];
    rs[i] = 1.f / s;
}

// ---------------- maxn over h2T bf16: two-stage ----------------
__global__ __launch_bounds__(256) void maxn1_k(const short* __restrict__ h2,
                                               float* __restrict__ gp) {
    int b = blockIdx.x, s = blockIdx.y, c = threadIdx.x;
    const short* p = h2 + ((long)b * GN + s * 128) * 256 + c;
    float m = -1e30f;
    for (int n = 0; n < 128; ++n) m = fmaxf(m, bf2f(p[(long)n * 256]));
    gp[((b * 16 + s) << 8) + c] = m;
}
__global__ __launch_bounds__(256) void maxn2_k(const float* __restrict__ gp,
                                               float* __restrict__ g) {
    int b = blockIdx.x, c = threadIdx.x;
    float m = -1e30f;
    for (int s = 0; s < 16; ++s) m = fmaxf(m, gp[((b * 16 + s) << 8) + c]);
    g[(b << 8) + c] = m;
}

// ---------------- cvec[b,o] = b3[o] + sum_c w3[o,256+c]*g[b,c] (fp32) ----------------
__global__ __launch_bounds__(256) void cvec_k(const float* __restrict__ w3,
                                              const float* __restrict__ b3,
                                              const float* __restrict__ g,
                                              float* __restrict__ cvec) {
    int idx = blockIdx.x * 256 + threadIdx.x;
    int b = idx >> 9, o = idx & 511;
    const float* gb = g + (b << 8);
    const float* wr = w3 + (long)o * 512 + 256;
    float s = b3[o];
    for (int c = 0; c < 256; ++c) s = fmaf(wr[c], gb[c], s);
    cvec[idx] = s;
}

// ---------------- column sums of attn = P * rs[q] over q (two-stage) ----------------
__global__ __launch_bounds__(256) void colsum1_k(const short* __restrict__ Ab,
                                                 const float* __restrict__ rs,
                                                 float* __restrict__ cp) {
    int kb = blockIdx.x, qs = blockIdx.y, z = blockIdx.z;
    int k = kb * 256 + threadIdx.x;
    const short* p = Ab + (long)z * GN * GN + (long)qs * 64 * GN + k;
    const float* rv = rs + z * GN + qs * 64;
    float s = 0.f;
    for (int qq = 0; qq < 64; ++qq) s += bf2f(p[(long)qq * GN]) * rv[qq];
    cp[((z * 32 + qs) * GN) + k] = s;
}
__global__ __launch_bounds__(256) void colsum2_k(const float* __restrict__ cp,
                                                 float* __restrict__ cs) {
    int k = blockIdx.x * 256 + threadIdx.x, z = blockIdx.y;
    float s = 1e-9f;
    for (int qs = 0; qs < 32; ++qs) s += cp[((z * 32 + qs) * GN) + k];
    cs[z * GN + k] = s;
}

// ---------------- xvc[c,p] /= cs[p]  (in place; folds L1 renorm into xv) ----------------
__global__ __launch_bounds__(256) void xvscale_k(short* __restrict__ xvc,
                                                 const float* __restrict__ cs) {
    long idx = ((long)blockIdx.x * 256 + threadIdx.x) * 4;  // over 512*32768
    int p = (int)(idx & 32767);
    short* ptr = xvc + idx;
    float4 cv = *(const float4*)(cs + p);
    uint2 u = *(const uint2*)ptr;
    short* sp = (short*)&u;
    sp[0] = f2bf(bf2f(sp[0]) / cv.x);
    sp[1] = f2bf(bf2f(sp[1]) / cv.y);
    sp[2] = f2bf(bf2f(sp[2]) / cv.z);
    sp[3] = f2bf(bf2f(sp[3]) / cv.w);
    *(uint2*)ptr = u;
}

// ---------------- BN scale/shift from fused GEMM stats [512][512] ----------------
// one block per channel (512 blocks) — R13's 2-block version was serial-bound
__global__ __launch_bounds__(256) void bn2_k(const float* __restrict__ bs1,
                                             const float* __restrict__ bs2,
                                             const float* __restrict__ gamma,
                                             const float* __restrict__ beta,
                                             float* __restrict__ sc,
                                             float* __restrict__ sh) {
    int c = blockIdx.x;
    float s = 0.f, s2 = 0.f;
    for (int i = threadIdx.x; i < 512; i += 256) {
        s += bs1[i * 512 + c];
        s2 += bs2[i * 512 + c];
    }
    s = block_sum(s);
    s2 = block_sum(s2);
    if (threadIdx.x == 0) {
        const float cnt = (float)(GB * GN);
        float mu = s / cnt;
        float var = s2 / cnt - mu * mu;
        float r = rsqrtf(var + 1e-5f);
        float gm = gamma[c] * r;
        sc[c] = gm;
        sh[c] = beta[c] - gm * mu;
    }
}

// ---------------- h4T = bf16(h3b + relu(d*sc+sh)) ----------------
__global__ __launch_bounds__(256) void bn_apply_k(const short* __restrict__ h3b,
                                                  const short* __restrict__ d,
                                                  const float* __restrict__ sc,
                                                  const float* __restrict__ sh,
                                                  short* __restrict__ h4) {
    long bidx = ((long)blockIdx.x * 256 + threadIdx.x) * 4;
    int c = (int)(bidx & 511);
    uint2 du = *(const uint2*)(d + bidx);
    short* ds = (short*)&du;
    uint2 hu = *(const uint2*)(h3b + bidx);
    short* hs = (short*)&hu;
    float4 a4 = *(const float4*)(sc + c);
    float4 b4 = *(const float4*)(sh + c);
    float r0 = bf2f(hs[0]) + fmaxf(fmaf(bf2f(ds[0]), a4.x, b4.x), 0.f);
    float r1 = bf2f(hs[1]) + fmaxf(fmaf(bf2f(ds[1]), a4.y, b4.y), 0.f);
    float r2 = bf2f(hs[2]) + fmaxf(fmaf(bf2f(ds[2]), a4.z, b4.z), 0.f);
    float r3 = bf2f(hs[3]) + fmaxf(fmaf(bf2f(ds[3]), a4.w, b4.w), 0.f);
    uint2 o;
    o.x = (unsigned short)f2bf(r0) | ((unsigned)(unsigned short)f2bf(r1) << 16);
    o.y = (unsigned short)f2bf(r2) | ((unsigned)(unsigned short)f2bf(r3) << 16);
    *(uint2*)(h4 + bidx) = o;
}

// ---------------- out[i] = max over 32 partials ----------------
__global__ __launch_bounds__(256) void max_final_k(const float* __restrict__ P,
                                                   float* __restrict__ out) {
    int i = blockIdx.x * 256 + threadIdx.x;
    const float* p = P + ((long)i << 5);
    float m = p[0];
#pragma unroll
    for (int j = 1; j < 32; ++j) m = fmaxf(m, p[j]);
    out[i] = m;
}

extern "C" void kernel_launch(void* const* d_in, const int* in_sizes, int n_in,
                              void* d_out, int out_size, void* d_ws, size_t ws_size,
                              hipStream_t stream) {
    const float* x = (const float*)d_in[0];
    const float* w1 = (const float*)d_in[1];
    const float* b1 = (const float*)d_in[2];
    const float* w2 = (const float*)d_in[3];
    const float* b2 = (const float*)d_in[4];
    const float* w3 = (const float*)d_in[5];
    const float* b3 = (const float*)d_in[6];
    const float* w4 = (const float*)d_in[7];
    const float* b4 = (const float*)d_in[8];
    const float* wqk = (const float*)d_in[9];
    const float* wv = (const float*)d_in[10];
    const float* bv = (const float*)d_in[11];
    const float* wt = (const float*)d_in[12];
    const float* bt = (const float*)d_in[13];
    const float* gamma = (const float*)d_in[14];
    const float* beta = (const float*)d_in[15];
    float* out = (float*)d_out;

    // ---- workspace carve (bytes), peak ~255.05 MB ----
    char* base = (char*)d_ws;
    short* h3b = (short*)base;                    // [32768,512] bf16 32 MB
    short* hsT = (short*)(base + 33554432);       // [32768,512] bf16 32 MB
    short* kT  = (short*)(base + 67108864);       // [32768,128] bf16  8 MB
    short* xvc = (short*)(base + 75497472);       // [512,32768] bf16 32 MB (channel-major)
    short* EA  = (short*)(base + 109051904);      // [16,2048,2048] bf16 128 MB (P = exp(E))
    short* h1T = (short*)(base + 109051904);      //   alias (early, dead before EA)
    short* h2T = (short*)(base + 117440512);      //   alias (early)
    short* dTb = (short*)(base + 109051904);      //   alias [32768,512] bf16 (late, EA dead)
    short* h4T = (short*)(base + 67108864);       //   alias 32 MB over kT+xvc (late)
    char* S = base + 243269632;
    float* gp   = (float*)(S);                    // 262144
    float* g    = (float*)(S + 262144);           // 16384
    float* cvec = (float*)(S + 278528);           // 32768
    float* cp   = (float*)(S + 311296);           // 4 MB [16,32,2048]; rp aliases (earlier)
    float* rp   = cp;                             //   [32768,32] row-sum partials (dead before cp)
    float* cs   = (float*)(S + 4505600);          // 128 KB [16,2048]
    float* bs1  = (float*)(S + 4636672);          // 1 MB [512,512] fused BN sum partials
    float* bs2  = (float*)(S + 5685248);          // 1 MB [512,512] fused BN sumsq partials
    float* bnsc = (float*)(S + 6733824);          // 2048
    float* bnsh = (float*)(S + 6735872);          // 2048
    float* Pmax = (float*)(S + 6737920);          // [16,1024,32] f32 = 2 MB
    short* w2b  = (short*)(S + 8835072);          // bf16 weights, CONTIGUOUS region:
    short* w3b  = (short*)(S + 8900608);          //   w2 32768 | w3 262144 | wqk 65536
    short* wqkb = (short*)(S + 9424896);          //   wv 262144 | wt 262144 | w4 524288
    short* wvb  = (short*)(S + 9555968);
    short* wtb  = (short*)(S + 10080256);
    short* w4b  = (short*)(S + 10604544);
    float* rs   = (float*)(S + 11653120);         // 128 KB [16,2048] 1/rowsum

    // 0. all weight converts in one kernel (dst region contiguous from w2b)
    f2ball_k<<<5505, 256, 0, stream>>>(w2, w3, wqk, wv, wt, w4, w2b);

    // 1. posenc + conv1 + relu -> h1T
    posenc_conv1_k<<<128, 256, 0, stream>>>(x, w1, b1, h1T);

    // 2. h2T = h1T @ w2^T + b2  (no relu)
    mm_k<2, 1, false><<<dim3(256, 2, 1), 256, 0, stream>>>(
        h1T, 128, 0, w2b, 128, 0, b2, 0, nullptr, 0, nullptr,
        nullptr, 0, h2T, 0, nullptr, nullptr, 256, 128);

    // 3. g[b,c] = max_n h2T
    maxn1_k<<<dim3(GB, 16), 256, 0, stream>>>(h2T, gp);
    maxn2_k<<<GB, 256, 0, stream>>>(gp, g);

    // 4. cvec = w3[:,256:] @ g + b3 (fp32)
    cvec_k<<<32, 256, 0, stream>>>(w3, b3, g, cvec);

    // 5. h3b = bf16(relu(h2T @ w3[:,:256]^T + cvec))
    mm_k<2, 3, true><<<dim3(256, 4, 1), 256, 0, stream>>>(
        h2T, 256, 0, w3b, 512, 0, cvec, 512, nullptr, 0, nullptr,
        nullptr, 0, h3b, 0, nullptr, nullptr, 512, 256);

    // 6. kT = h3b @ wqk^T
    mm_k<2, 0, false><<<dim3(256, 1, 1), 256, 0, stream>>>(
        h3b, 512, 0, wqkb, 512, 0, nullptr, 0, nullptr, 0, nullptr,
        nullptr, 0, kT, 0, nullptr, nullptr, 128, 512);

    // 7. xv channel-major: D[c, point] = wv @ h3 + bv(row)
    mm_k<2, 2, false><<<dim3(4, 256, 1), 256, 0, stream>>>(
        wvb, 512, 0, h3b, 512, 0, bv, 0, nullptr, 0, nullptr,
        nullptr, 0, xvc, 0, nullptr, nullptr, 32768, 512);

    // 8. attention, all 16 batches, softmax fused into energy epilogue
    // 8a. P = exp(kT kT^T) bf16 + row-sum partials rp
    mm_k<6, 0, false><<<dim3(16, 16, 16), 256, 0, stream>>>(
        kT, 128, (long long)GN * 128, kT, 128, (long long)GN * 128,
        nullptr, 0, nullptr, 0, nullptr, nullptr, 0,
        EA, (long long)GN * GN, rp, nullptr, GN, 128);
    // 8b. rs = 1/rowsum
    rs_k<<<128, 256, 0, stream>>>(rp, rs);
    // 8c. column sums of attn = P*rs
    colsum1_k<<<dim3(8, 32, GB), 256, 0, stream>>>(EA, rs, cp);
    colsum2_k<<<dim3(8, GB), 256, 0, stream>>>(cp, cs);
    // 8d. fold L1 renorm into xv (in place)
    xvscale_k<<<16384, 256, 0, stream>>>(xvc, cs);
    // 8e. hsT = bf16(h3b - rs[q] * (P @ xv'^T))
    mm_k<4, 0, false><<<dim3(16, 4, 16), 256, 0, stream>>>(
        EA, GN, (long long)GN * GN,
        xvc, 32768, (long long)GN,
        nullptr, 0,
        h3b, (long long)GN * 512, rs,
        nullptr, 0,
        hsT, (long long)GN * 512,
        nullptr, nullptr, 512, GN);

    // 9. dTb = bf16(hsT @ wt^T + bt) + fused BN stat partials (bs1/bs2)
    mm_k<2, 1, false, true><<<dim3(256, 4, 1), 256, 0, stream>>>(
        hsT, 512, 0, wtb, 512, 0, bt, 0, nullptr, 0, nullptr,
        nullptr, 0, dTb, 0, bs1, bs2, 512, 512);

    // 10. BN scale/shift from fused stats (512 blocks — parallel)
    bn2_k<<<512, 256, 0, stream>>>(bs1, bs2, gamma, beta, bnsc, bnsh);

    // 11. h4T = bf16(h3b + relu(bn(dTb)))
    bn_apply_k<<<16384, 256, 0, stream>>>(h3b, dTb, bnsc, bnsh, h4T);

    // 12. fused final conv + per-wave-tile col max -> Pmax [16,1024,32]
    mm_k<5, 1, false><<<dim3(256, 8, 1), 256, 0, stream>>>(
        h4T, 512, 0, w4b, 512, 0, b4, 0, nullptr, 0, nullptr,
        nullptr, 0, nullptr, 0, Pmax, nullptr, 1024, 512);

    // 13. out = max over tiles
    max_final_k<<<64, 256, 0, stream>>>(Pmax, out);
}

// Round 15
// 506.937 us; speedup vs baseline: 1.2426x; 1.0077x over previous
//
#include <hip/hip_runtime.h>
#include <cmath>

#define GN 2048
#define GB 16

typedef __attribute__((ext_vector_type(8))) short bf8_t;
typedef __attribute__((ext_vector_type(4))) float f4_t;

__device__ __forceinline__ short f2bf(float f) {
    union { float f; unsigned u; } v; v.f = f;
    unsigned r = v.u + 0x7FFFu + ((v.u >> 16) & 1u);
    return (short)(r >> 16);
}
__device__ __forceinline__ float bf2f(short s) {
    union { unsigned u; float f; } v; v.u = ((unsigned)(unsigned short)s) << 16;
    return v.f;
}

// async 16B/lane global->LDS (wave-uniform LDS base, lane i lands at base+i*16)
__device__ __forceinline__ void load16_lds(const short* g, short* l) {
    __builtin_amdgcn_global_load_lds(
        (const __attribute__((address_space(1))) unsigned int*)g,
        (__attribute__((address_space(3))) unsigned int*)l, 16, 0, 0);
}

// ---------------- reductions ----------------
__device__ __forceinline__ float wave_max(float v) {
#pragma unroll
    for (int o = 32; o > 0; o >>= 1) v = fmaxf(v, __shfl_xor(v, o, 64));
    return v;
}
__device__ __forceinline__ float wave_sum(float v) {
#pragma unroll
    for (int o = 32; o > 0; o >>= 1) v += __shfl_xor(v, o, 64);
    return v;
}
__device__ __forceinline__ float block_sum(float v) {
    __shared__ float sm[4];
    v = wave_sum(v);
    if ((threadIdx.x & 63) == 0) sm[threadIdx.x >> 6] = v;
    __syncthreads();
    v = sm[0] + sm[1] + sm[2] + sm[3];
    __syncthreads();
    return v;
}

// ---------------- fused fp32 -> bf16 weight convert (dst region contiguous) ----------------
__global__ __launch_bounds__(256) void f2ball_k(
    const float* __restrict__ w2, const float* __restrict__ w3,
    const float* __restrict__ wqk, const float* __restrict__ wv,
    const float* __restrict__ wt, const float* __restrict__ w4,
    short* __restrict__ dst) {
    int i = blockIdx.x * 256 + threadIdx.x;
    if (i >= 1409024) return;
    float v;
    if (i < 32768) v = w2[i];
    else if (i < 294912) v = w3[i - 32768];
    else if (i < 360448) v = wqk[i - 294912];
    else if (i < 622592) v = wv[i - 360448];
    else if (i < 884736) v = wt[i - 622592];
    else v = w4[i - 884736];
    dst[i] = f2bf(v);
}

// ---------------- posenc + conv1 + relu -> h1T [32768, 128] bf16 ----------------
__global__ __launch_bounds__(256) void posenc_conv1_k(
    const float* __restrict__ x, const float* __restrict__ w1,
    const float* __restrict__ b1, short* __restrict__ h1) {
    __shared__ float w[128 * 21];
    __shared__ float bb[128];
    __shared__ float se[256][21];
    const int tid = threadIdx.x;
    for (int i = tid; i < 128 * 21; i += 256) w[i] = w1[i];
    if (tid < 128) bb[tid] = b1[tid];
    int p0 = blockIdx.x * 256;
    int p = p0 + tid, b = p >> 11, n = p & (GN - 1);
    const float* xb = x + (long)b * 3 * GN + n;
    float t0 = xb[0], t1 = xb[GN], t2 = xb[2 * GN];
    se[tid][0] = t0; se[tid][1] = t1; se[tid][2] = t2;
    se[tid][3] = sinf(t0); se[tid][4] = sinf(t1); se[tid][5] = sinf(t2);
    se[tid][6] = cosf(t0); se[tid][7] = cosf(t1); se[tid][8] = cosf(t2);
    se[tid][9] = sinf(2.f * t0); se[tid][10] = sinf(2.f * t1); se[tid][11] = sinf(2.f * t2);
    se[tid][12] = cosf(2.f * t0); se[tid][13] = cosf(2.f * t1); se[tid][14] = cosf(2.f * t2);
    se[tid][15] = sinf(4.f * t0); se[tid][16] = sinf(4.f * t1); se[tid][17] = sinf(4.f * t2);
    se[tid][18] = cosf(4.f * t0); se[tid][19] = cosf(4.f * t1); se[tid][20] = cosf(4.f * t2);
    __syncthreads();
    short* outb = h1 + (long)p0 * 128;
    for (int it = 0; it < 128; ++it) {
        int L = it * 256 + tid;
        int pl = L >> 7, o = L & 127;
        float s = bb[o];
        const float* er = se[pl];
        const float* wr = &w[o * 21];
#pragma unroll
        for (int c = 0; c < 21; ++c) s = fmaf(wr[c], er[c], s);
        outb[L] = f2bf(fmaxf(s, 0.f));
    }
}

// ---------------- MFMA GEMM: D[row,col] = sum_k A[row,k]*B[col,k] ----------------
// R14 engine (measured best): 256 threads, 128x128 block tile, BK=64
// (two back-to-back BK=32 sub-tiles per barrier pair), block-SHARED
// single-buffered LDS staged cooperatively via global_load_lds, 2-barrier loop.
// CORRECTNESS: each wave must explicitly s_waitcnt vmcnt(0) BEFORE signaling
// the barrier (LDS-DMA is not drained by __syncthreads on this toolchain).
// 32 KB LDS/block. XOR-swizzled: 16B-slot p of row holds k-block p^((row>>1)&3).
// Grid: blockIdx.x = row tile (M/128), blockIdx.y = col tile (N/128), z = batch.
// MODE: 1=f32 out, 2=bf16 out, 4=Cb=bf16(aux - rs[row]*D), 5=col-max partials,
//       6=Cb=bf16(exp(D)) + per-tile row-sum partials into Pmax (rp).
// BIAS: 0 none, 1 per-col, 2 per-row, 3 per-col (cvec rows per batch).
// STATS (MODE 2): emit per-column (sum,sum^2) over this wave's 64 rows into
// Pmax/Ps2[rw2*512+gcol], rw2 = blockIdx.x*2+wr — fuses BN stats.
// COLMAX (MODE 2): emit per-(batch,column) max partials over this wave's 64
// rows into Pmax[((b*ldc+gcol)<<5) + rw], rw = (blockIdx.x*2+wr)&31 — fuses
// the global-max pooling (g) into the h2 conv.
template <int MODE, int BIAS, bool RELU, bool STATS = false, bool COLMAX = false>
__global__ __launch_bounds__(256) void mm_k(
    const short* __restrict__ A, int lda, long long aB,
    const short* __restrict__ B, int ldb, long long bB,
    const float* __restrict__ bias, int biasStride,
    const short* __restrict__ aux, long long auxB,
    const float* __restrict__ rsv,
    float* __restrict__ Cf, long long cfB,
    short* __restrict__ Cb, long long cbB,
    float* __restrict__ Pmax, float* __restrict__ Ps2,
    int ldc, int K) {
    const int z = blockIdx.z;
    A += (long long)z * aB;
    B += (long long)z * bB;
    if (MODE == 4) { aux += (long long)z * auxB; rsv += (long long)z * GN; }
    if (MODE == 1) Cf += (long long)z * cfB;
    if (MODE == 2 || MODE == 4 || MODE == 6) Cb += (long long)z * cbB;
    if (MODE == 6) Pmax += (long long)z * GN * 32;
    const int row0 = blockIdx.x * 128, col0 = blockIdx.y * 128;
    const int tid = threadIdx.x;
    const int lane = tid & 63, w = tid >> 6;
    const int r = lane & 15, q = lane >> 4;
    const int wr = w >> 1, wc = w & 1;

    __shared__ short lA[8192];  // 2 sub-tiles x [128 rows][32 k] swizzled
    __shared__ short lB[8192];

    f4_t acc[4][4] = {};

    // cooperative staging: wave w covers rows w*32 .. w*32+31 (two 16-row DMAs
    // per operand per sub-tile)
    const int sRow = lane >> 2;                       // 0..15
    const int sKb = (lane & 3) ^ ((lane >> 3) & 3);   // swizzled source k-block
    const long aG = (long)(row0 + w * 32 + sRow) * lda + sKb * 8;
    const long bG = (long)(col0 + w * 32 + sRow) * ldb + sKb * 8;
    short* ldsA0 = lA + (w * 32) * 32;
    short* ldsA1 = lA + (w * 32 + 16) * 32;
    short* ldsB0 = lB + (w * 32) * 32;
    short* ldsB1 = lB + (w * 32 + 16) * 32;

    // swizzled k-invariant fragment read offsets (shorts, within one sub-tile)
    const int sw = (q ^ ((r >> 1) & 3)) * 8;
    int aoff[4], boff[4];
#pragma unroll
    for (int i = 0; i < 4; ++i) {
        aoff[i] = (wr * 64 + i * 16 + r) * 32 + sw;
        boff[i] = (wc * 64 + i * 16 + r) * 32 + sw;
    }

    for (int k0 = 0; k0 < K; k0 += 64) {
        __syncthreads();  // previous tile fully consumed (lgkm dep-waits before MFMA use)
        load16_lds(A + aG + k0, ldsA0);
        load16_lds(A + aG + (long)16 * lda + k0, ldsA1);
        load16_lds(B + bG + k0, ldsB0);
        load16_lds(B + bG + (long)16 * ldb + k0, ldsB1);
        load16_lds(A + aG + k0 + 32, ldsA0 + 4096);
        load16_lds(A + aG + (long)16 * lda + k0 + 32, ldsA1 + 4096);
        load16_lds(B + bG + k0 + 32, ldsB0 + 4096);
        load16_lds(B + bG + (long)16 * ldb + k0 + 32, ldsB1 + 4096);
        asm volatile("s_waitcnt vmcnt(0)" ::: "memory");  // DRAIN own LDS-DMA before barrier
        __syncthreads();  // all waves drained -> full tile visible
#pragma unroll
        for (int h = 0; h < 2; ++h) {
            const short* la = lA + h * 4096;
            const short* lb = lB + h * 4096;
            bf8_t av[4], bv[4];
#pragma unroll
            for (int i = 0; i < 4; ++i) av[i] = *(const bf8_t*)(la + aoff[i]);
#pragma unroll
            for (int j = 0; j < 4; ++j) bv[j] = *(const bf8_t*)(lb + boff[j]);
#pragma unroll
            for (int i = 0; i < 4; ++i)
#pragma unroll
                for (int j = 0; j < 4; ++j)
                    acc[i][j] = __builtin_amdgcn_mfma_f32_16x16x32_bf16(av[i], bv[j], acc[i][j], 0, 0, 0);
        }
    }

    if constexpr (MODE == 5) {
        // per-column max over this wave's 64 rows (pure shuffle)
        int b = row0 >> 11;
        int rw = (blockIdx.x * 2 + wr) & 31;  // row-wave index within batch
#pragma unroll
        for (int j = 0; j < 4; ++j) {
            float vm = -1e30f;
#pragma unroll
            for (int i = 0; i < 4; ++i)
#pragma unroll
                for (int e = 0; e < 4; ++e) vm = fmaxf(vm, acc[i][j][e]);
            vm = fmaxf(vm, __shfl_xor(vm, 16, 64));
            vm = fmaxf(vm, __shfl_xor(vm, 32, 64));
            if (q == 0) {
                int gcol = col0 + wc * 64 + j * 16 + r;
                Pmax[(((long)b * 1024 + gcol) << 5) + rw] = vm + bias[gcol];
            }
        }
    } else if constexpr (MODE == 6) {
        // P = exp(E) bf16 + per-tile row sums -> rp[row][blockIdx.y*2+wc]
        float rsum[4][4] = {};
#pragma unroll
        for (int j = 0; j < 4; ++j) {
            int gcol = col0 + wc * 64 + j * 16 + r;
#pragma unroll
            for (int i = 0; i < 4; ++i) {
#pragma unroll
                for (int e = 0; e < 4; ++e) {
                    int grow = row0 + wr * 64 + i * 16 + q * 4 + e;
                    float ex = __expf(acc[i][j][e]);
                    rsum[i][e] += ex;
                    Cb[(long)grow * ldc + gcol] = f2bf(ex);
                }
            }
        }
#pragma unroll
        for (int i = 0; i < 4; ++i)
#pragma unroll
            for (int e = 0; e < 4; ++e) {
                float v = rsum[i][e];
                v += __shfl_xor(v, 1, 64);
                v += __shfl_xor(v, 2, 64);
                v += __shfl_xor(v, 4, 64);
                v += __shfl_xor(v, 8, 64);
                if (r == 0) {
                    int grow = row0 + wr * 64 + i * 16 + q * 4 + e;
                    Pmax[((long)grow << 5) + blockIdx.y * 2 + wc] = v;
                }
            }
    } else if constexpr (MODE == 4) {
        // hs = bf16(aux - rs[row] * D)
#pragma unroll
        for (int i = 0; i < 4; ++i) {
#pragma unroll
            for (int e = 0; e < 4; ++e) {
                int grow = row0 + wr * 64 + i * 16 + q * 4 + e;
                float rsr = rsv[grow];
                long ob = (long)grow * ldc + col0 + wc * 64 + r;
#pragma unroll
                for (int j = 0; j < 4; ++j) {
                    long off = ob + j * 16;
                    Cb[off] = f2bf(bf2f(aux[off]) - acc[i][j][e] * rsr);
                }
            }
        }
    } else {
        const int b2d = (BIAS == 3) ? (row0 >> 11) : 0;
#pragma unroll
        for (int j = 0; j < 4; ++j) {
            int gcol = col0 + wc * 64 + j * 16 + r;
            float bvv = 0.f;
            if constexpr (BIAS == 1) bvv = bias[gcol];
            if constexpr (BIAS == 3) bvv = bias[b2d * biasStride + gcol];
            float s1 = 0.f, s2 = 0.f;
            float cmx = -1e30f;
#pragma unroll
            for (int i = 0; i < 4; ++i) {
#pragma unroll
                for (int e = 0; e < 4; ++e) {
                    int grow = row0 + wr * 64 + i * 16 + q * 4 + e;
                    float v = acc[i][j][e] + bvv;
                    if constexpr (BIAS == 2) v += bias[grow];
                    if constexpr (RELU) v = fmaxf(v, 0.f);
                    if constexpr (STATS) { s1 += v; s2 = fmaf(v, v, s2); }
                    if constexpr (COLMAX) cmx = fmaxf(cmx, v);
                    long off = (long)grow * ldc + gcol;
                    if constexpr (MODE == 1) Cf[off] = v;
                    if constexpr (MODE == 2) Cb[off] = f2bf(v);
                }
            }
            if constexpr (STATS) {
                s1 += __shfl_xor(s1, 16, 64); s1 += __shfl_xor(s1, 32, 64);
                s2 += __shfl_xor(s2, 16, 64); s2 += __shfl_xor(s2, 32, 64);
                if (q == 0) {
                    int rw2 = blockIdx.x * 2 + wr;  // 0..511 row-wave index
                    Pmax[rw2 * 512 + gcol] = s1;
                    Ps2[rw2 * 512 + gcol] = s2;
                }
            }
            if constexpr (COLMAX) {
                cmx = fmaxf(cmx, __shfl_xor(cmx, 16, 64));
                cmx = fmaxf(cmx, __shfl_xor(cmx, 32, 64));
                if (q == 0) {
                    int b = row0 >> 11;
                    int rw = (blockIdx.x * 2 + wr) & 31;  // row-wave within batch
                    Pmax[(((long)b * ldc + gcol) << 5) + rw] = cmx;
                }
            }
        }
    }
}

// ---------------- rs[q] = 1 / sum of 32 row partials ----------------
__global__ __launch_bounds__(256) void rs_k(const float* __restrict__ rp,
                                            float* __restrict__ rs) {
    int i = blockIdx.x * 256 + threadIdx.x;  // 0..32767
    const float* p = rp + ((long)i << 5);
    float s = 0.f;
#pragma unroll
    for (int j = 0; j < 32; ++j) s += p[j];
    rs[i] = 1.f / s;
}

// ---------------- g[i] = max over 32 partials (fused h2 colmax reduce) ----------------
__global__ __launch_bounds__(256) void maxg_k(const float* __restrict__ P,
                                              float* __restrict__ g) {
    int i = blockIdx.x * 256 + threadIdx.x;  // 0..4095 (16 batches x 256 ch)
    const float* p = P + ((long)i << 5);
    float m = p[0];
#pragma unroll
    for (int j = 1; j < 32; ++j) m = fmaxf(m, p[j]);
    g[i] = m;
}

// ---------------- cvec[b,o] = b3[o] + sum_c w3[o,256+c]*g[b,c] (fp32) ----------------
__global__ __launch_bounds__(256) void cvec_k(const float* __restrict__ w3,
                                              const float* __restrict__ b3,
                                              const float* __restrict__ g,
                                              float* __restrict__ cvec) {
    int idx = blockIdx.x * 256 + threadIdx.x;
    int b = idx >> 9, o = idx & 511;
    const float* gb = g + (b << 8);
    const float* wr = w3 + (long)o * 512 + 256;
    float s = b3[o];
    for (int c = 0; c < 256; ++c) s = fmaf(wr[c], gb[c], s);
    cvec[idx] = s;
}

// ---------------- column sums of attn = P * rs[q] over q (two-stage) ----------------
__global__ __launch_bounds__(256) void colsum1_k(const short* __restrict__ Ab,
                                                 const float* __restrict__ rs,
                                                 float* __restrict__ cp) {
    int kb = blockIdx.x, qs = blockIdx.y, z = blockIdx.z;
    int k = kb * 256 + threadIdx.x;
    const short* p = Ab + (long)z * GN * GN + (long)qs * 64 * GN + k;
    const float* rv = rs + z * GN + qs * 64;
    float s = 0.f;
    for (int qq = 0; qq < 64; ++qq) s += bf2f(p[(long)qq * GN]) * rv[qq];
    cp[((z * 32 + qs) * GN) + k] = s;
}
__global__ __launch_bounds__(256) void colsum2_k(const float* __restrict__ cp,
                                                 float* __restrict__ cs) {
    int k = blockIdx.x * 256 + threadIdx.x, z = blockIdx.y;
    float s = 1e-9f;
    for (int qs = 0; qs < 32; ++qs) s += cp[((z * 32 + qs) * GN) + k];
    cs[z * GN + k] = s;
}

// ---------------- xvc[c,p] /= cs[p]  (in place; folds L1 renorm into xv) ----------------
__global__ __launch_bounds__(256) void xvscale_k(short* __restrict__ xvc,
                                                 const float* __restrict__ cs) {
    long idx = ((long)blockIdx.x * 256 + threadIdx.x) * 4;  // over 512*32768
    int p = (int)(idx & 32767);
    short* ptr = xvc + idx;
    float4 cv = *(const float4*)(cs + p);
    uint2 u = *(const uint2*)ptr;
    short* sp = (short*)&u;
    sp[0] = f2bf(bf2f(sp[0]) / cv.x);
    sp[1] = f2bf(bf2f(sp[1]) / cv.y);
    sp[2] = f2bf(bf2f(sp[2]) / cv.z);
    sp[3] = f2bf(bf2f(sp[3]) / cv.w);
    *(uint2*)ptr = u;
}

// ---------------- BN scale/shift from fused GEMM stats [512][512] ----------------
// one block per channel (512 blocks) — R13's 2-block version was serial-bound
__global__ __launch_bounds__(256) void bn2_k(const float* __restrict__ bs1,
                                             const float* __restrict__ bs2,
                                             const float* __restrict__ gamma,
                                             const float* __restrict__ beta,
                                             float* __restrict__ sc,
                                             float* __restrict__ sh) {
    int c = blockIdx.x;
    float s = 0.f, s2 = 0.f;
    for (int i = threadIdx.x; i < 512; i += 256) {
        s += bs1[i * 512 + c];
        s2 += bs2[i * 512 + c];
    }
    s = block_sum(s);
    s2 = block_sum(s2);
    if (threadIdx.x == 0) {
        const float cnt = (float)(GB * GN);
        float mu = s / cnt;
        float var = s2 / cnt - mu * mu;
        float r = rsqrtf(var + 1e-5f);
        float gm = gamma[c] * r;
        sc[c] = gm;
        sh[c] = beta[c] - gm * mu;
    }
}

// ---------------- h4T = bf16(h3b + relu(d*sc+sh)) ----------------
__global__ __launch_bounds__(256) void bn_apply_k(const short* __restrict__ h3b,
                                                  const short* __restrict__ d,
                                                  const float* __restrict__ sc,
                                                  const float* __restrict__ sh,
                                                  short* __restrict__ h4) {
    long bidx = ((long)blockIdx.x * 256 + threadIdx.x) * 4;
    int c = (int)(bidx & 511);
    uint2 du = *(const uint2*)(d + bidx);
    short* ds = (short*)&du;
    uint2 hu = *(const uint2*)(h3b + bidx);
    short* hs = (short*)&hu;
    float4 a4 = *(const float4*)(sc + c);
    float4 b4 = *(const float4*)(sh + c);
    float r0 = bf2f(hs[0]) + fmaxf(fmaf(bf2f(ds[0]), a4.x, b4.x), 0.f);
    float r1 = bf2f(hs[1]) + fmaxf(fmaf(bf2f(ds[1]), a4.y, b4.y), 0.f);
    float r2 = bf2f(hs[2]) + fmaxf(fmaf(bf2f(ds[2]), a4.z, b4.z), 0.f);
    float r3 = bf2f(hs[3]) + fmaxf(fmaf(bf2f(ds[3]), a4.w, b4.w), 0.f);
    uint2 o;
    o.x = (unsigned short)f2bf(r0) | ((unsigned)(unsigned short)f2bf(r1) << 16);
    o.y = (unsigned short)f2bf(r2) | ((unsigned)(unsigned short)f2bf(r3) << 16);
    *(uint2*)(h4 + bidx) = o;
}

// ---------------- out[i] = max over 32 partials ----------------
__global__ __launch_bounds__(256) void max_final_k(const float* __restrict__ P,
                                                   float* __restrict__ out) {
    int i = blockIdx.x * 256 + threadIdx.x;
    const float* p = P + ((long)i << 5);
    float m = p[0];
#pragma unroll
    for (int j = 1; j < 32; ++j) m = fmaxf(m, p[j]);
    out[i] = m;
}

extern "C" void kernel_launch(void* const* d_in, const int* in_sizes, int n_in,
                              void* d_out, int out_size, void* d_ws, size_t ws_size,
                              hipStream_t stream) {
    const float* x = (const float*)d_in[0];
    const float* w1 = (const float*)d_in[1];
    const float* b1 = (const float*)d_in[2];
    const float* w2 = (const float*)d_in[3];
    const float* b2 = (const float*)d_in[4];
    const float* w3 = (const float*)d_in[5];
    const float* b3 = (const float*)d_in[6];
    const float* w4 = (const float*)d_in[7];
    const float* b4 = (const float*)d_in[8];
    const float* wqk = (const float*)d_in[9];
    const float* wv = (const float*)d_in[10];
    const float* bv = (const float*)d_in[11];
    const float* wt = (const float*)d_in[12];
    const float* bt = (const float*)d_in[13];
    const float* gamma = (const float*)d_in[14];
    const float* beta = (const float*)d_in[15];
    float* out = (float*)d_out;

    // ---- workspace carve (bytes), peak ~255.05 MB (unchanged from R14) ----
    char* base = (char*)d_ws;
    short* h3b = (short*)base;                    // [32768,512] bf16 32 MB
    short* hsT = (short*)(base + 33554432);       // [32768,512] bf16 32 MB
    short* kT  = (short*)(base + 67108864);       // [32768,128] bf16  8 MB
    short* xvc = (short*)(base + 75497472);       // [512,32768] bf16 32 MB (channel-major)
    short* EA  = (short*)(base + 109051904);      // [16,2048,2048] bf16 128 MB (P = exp(E))
    short* h1T = (short*)(base + 109051904);      //   alias (early, dead before EA)
    short* h2T = (short*)(base + 117440512);      //   alias (early)
    short* dTb = (short*)(base + 109051904);      //   alias [32768,512] bf16 (late, EA dead)
    short* h4T = (short*)(base + 67108864);       //   alias 32 MB over kT+xvc (late)
    char* S = base + 243269632;
    float* g    = (float*)(S + 262144);           // 16384
    float* cvec = (float*)(S + 278528);           // 32768
    float* cp   = (float*)(S + 311296);           // 4 MB [16,32,2048]; rp aliases (earlier)
    float* rp   = cp;                             //   [32768,32] row-sum partials (dead before cp)
    float* cs   = (float*)(S + 4505600);          // 128 KB [16,2048]
    float* bs1  = (float*)(S + 4636672);          // 1 MB [512,512] fused BN sum partials
    float* bs2  = (float*)(S + 5685248);          // 1 MB [512,512] fused BN sumsq partials
    float* bnsc = (float*)(S + 6733824);          // 2048
    float* bnsh = (float*)(S + 6735872);          // 2048
    float* Pmax = (float*)(S + 6737920);          // 2 MB: gmax partials (early) / h5 max partials (late)
    short* w2b  = (short*)(S + 8835072);          // bf16 weights, CONTIGUOUS region:
    short* w3b  = (short*)(S + 8900608);          //   w2 32768 | w3 262144 | wqk 65536
    short* wqkb = (short*)(S + 9424896);          //   wv 262144 | wt 262144 | w4 524288
    short* wvb  = (short*)(S + 9555968);
    short* wtb  = (short*)(S + 10080256);
    short* w4b  = (short*)(S + 10604544);
    float* rs   = (float*)(S + 11653120);         // 128 KB [16,2048] 1/rowsum

    // 0. all weight converts in one kernel (dst region contiguous from w2b)
    f2ball_k<<<5505, 256, 0, stream>>>(w2, w3, wqk, wv, wt, w4, w2b);

    // 1. posenc + conv1 + relu -> h1T
    posenc_conv1_k<<<128, 256, 0, stream>>>(x, w1, b1, h1T);

    // 2. h2T = h1T @ w2^T + b2 (no relu) + fused per-batch col-max partials
    mm_k<2, 1, false, false, true><<<dim3(256, 2, 1), 256, 0, stream>>>(
        h1T, 128, 0, w2b, 128, 0, b2, 0, nullptr, 0, nullptr,
        nullptr, 0, h2T, 0, Pmax, nullptr, 256, 128);

    // 3. g[b,c] = max over 32 partials
    maxg_k<<<16, 256, 0, stream>>>(Pmax, g);

    // 4. cvec = w3[:,256:] @ g + b3 (fp32)
    cvec_k<<<32, 256, 0, stream>>>(w3, b3, g, cvec);

    // 5. h3b = bf16(relu(h2T @ w3[:,:256]^T + cvec))
    mm_k<2, 3, true><<<dim3(256, 4, 1), 256, 0, stream>>>(
        h2T, 256, 0, w3b, 512, 0, cvec, 512, nullptr, 0, nullptr,
        nullptr, 0, h3b, 0, nullptr, nullptr, 512, 256);

    // 6. kT = h3b @ wqk^T
    mm_k<2, 0, false><<<dim3(256, 1, 1), 256, 0, stream>>>(
        h3b, 512, 0, wqkb, 512, 0, nullptr, 0, nullptr, 0, nullptr,
        nullptr, 0, kT, 0, nullptr, nullptr, 128, 512);

    // 7. xv channel-major: D[c, point] = wv @ h3 + bv(row)
    mm_k<2, 2, false><<<dim3(4, 256, 1), 256, 0, stream>>>(
        wvb, 512, 0, h3b, 512, 0, bv, 0, nullptr, 0, nullptr,
        nullptr, 0, xvc, 0, nullptr, nullptr, 32768, 512);

    // 8. attention, all 16 batches, softmax fused into energy epilogue
    // 8a. P = exp(kT kT^T) bf16 + row-sum partials rp
    mm_k<6, 0, false><<<dim3(16, 16, 16), 256, 0, stream>>>(
        kT, 128, (long long)GN * 128, kT, 128, (long long)GN * 128,
        nullptr, 0, nullptr, 0, nullptr, nullptr, 0,
        EA, (long long)GN * GN, rp, nullptr, GN, 128);
    // 8b. rs = 1/rowsum
    rs_k<<<128, 256, 0, stream>>>(rp, rs);
    // 8c. column sums of attn = P*rs
    colsum1_k<<<dim3(8, 32, GB), 256, 0, stream>>>(EA, rs, cp);
    colsum2_k<<<dim3(8, GB), 256, 0, stream>>>(cp, cs);
    // 8d. fold L1 renorm into xv (in place)
    xvscale_k<<<16384, 256, 0, stream>>>(xvc, cs);
    // 8e. hsT = bf16(h3b - rs[q] * (P @ xv'^T))
    mm_k<4, 0, false><<<dim3(16, 4, 16), 256, 0, stream>>>(
        EA, GN, (long long)GN * GN,
        xvc, 32768, (long long)GN,
        nullptr, 0,
        h3b, (long long)GN * 512, rs,
        nullptr, 0,
        hsT, (long long)GN * 512,
        nullptr, nullptr, 512, GN);

    // 9. dTb = bf16(hsT @ wt^T + bt) + fused BN stat partials (bs1/bs2)
    mm_k<2, 1, false, true><<<dim3(256, 4, 1), 256, 0, stream>>>(
        hsT, 512, 0, wtb, 512, 0, bt, 0, nullptr, 0, nullptr,
        nullptr, 0, dTb, 0, bs1, bs2, 512, 512);

    // 10. BN scale/shift from fused stats (512 blocks — parallel)
    bn2_k<<<512, 256, 0, stream>>>(bs1, bs2, gamma, beta, bnsc, bnsh);

    // 11. h4T = bf16(h3b + relu(bn(dTb)))
    bn_apply_k<<<16384, 256, 0, stream>>>(h3b, dTb, bnsc, bnsh, h4T);

    // 12. fused final conv + per-wave-tile col max -> Pmax [16,1024,32]
    mm_k<5, 1, false><<<dim3(256, 8, 1), 256, 0, stream>>>(
        h4T, 512, 0, w4b, 512, 0, b4, 0, nullptr, 0, nullptr,
        nullptr, 0, nullptr, 0, Pmax, nullptr, 1024, 512);

    // 13. out = max over tiles
    max_final_k<<<64, 256, 0, stream>>>(Pmax, out);
}